// Round 8
// baseline (88.729 us; speedup 1.0000x reference)
//
#include <hip/hip_runtime.h>
#include <math.h>

static constexpr float PI_F = 3.14159265358979323846f;

// ws: per-block segment partials, 96 floats per block: [g*3+{0,1,2}] = {sum0, sum1, count}
// Plain stores only -> no initialization needed (poison-immune).

__device__ inline void rot2(float p, float t, float o, float R[2][2][2]) {
    // Rot(p,t,o) = Rz(o) Ry(t) Rz(p)
    float ct = cosf(0.5f*t), st = sinf(0.5f*t);
    float apo = 0.5f*(p+o), amo = 0.5f*(p-o);
    R[0][0][0] =  ct*cosf(apo); R[0][0][1] = -ct*sinf(apo);
    R[0][1][0] = -st*cosf(amo); R[0][1][1] = -st*sinf(amo);
    R[1][0][0] =  st*cosf(amo); R[1][0][1] = -st*sinf(amo);
    R[1][1][0] =  ct*cosf(apo); R[1][1][1] =  ct*sinf(apo);
}

// One fused kernel: 256 thr/block, 128 nodes/block, 2 threads per node (h-split pair).
// Per node: 3 edge MLPs (a-col) + own node MLP (a,b) + 3 neighbor node MLPs (a-col, recomputed)
// + analytic circuit + upd MLP + LayerNorm + per-block segment partials.
__global__ __launch_bounds__(256, 1) void k_all(
    const float* __restrict__ node_feat, const float* __restrict__ edge_attr,
    const float* __restrict__ nW1, const float* __restrict__ nb1,
    const float* __restrict__ nW2, const float* __restrict__ nb2,
    const float* __restrict__ eW1, const float* __restrict__ eb1,
    const float* __restrict__ eW2, const float* __restrict__ eb2,
    const float* __restrict__ uW1, const float* __restrict__ ub1,
    const float* __restrict__ uW2, const float* __restrict__ ub2,
    const float* __restrict__ inits, const float* __restrict__ update,
    const float* __restrict__ lng, const float* __restrict__ lnb,
    const int* __restrict__ sub_nodes, const int* __restrict__ sub_edges,
    const int* __restrict__ batch,
    float* __restrict__ part, int N)
{
    __shared__ __align__(16) float sN[128*20]; // {W1t[0..15], b1, w2a, w2b, pad}
    __shared__ __align__(16) float sE[128*12]; // {W1t[0..7], b1, w2a, pad, pad}
    __shared__ __align__(16) float sU[128*12]; // {W1t[0..5], b1, w2a, w2b, pad x3}
    __shared__ float4 sPhi[64];
    __shared__ float  sUm[32];
    __shared__ float  sseg[96];
    const int tid = threadIdx.x;

    // ---- stage weights (coalesced global reads, transposed packed rows) ----
    for (int idx = tid; idx < 2048; idx += 256) sN[(idx&127)*20 + (idx>>7)] = nW1[idx];
    for (int idx = tid; idx < 1024; idx += 256) sE[(idx&127)*12 + (idx>>7)] = eW1[idx];
    for (int idx = tid; idx < 768;  idx += 256) sU[(idx&127)*12 + (idx>>7)] = uW1[idx];
    if (tid < 128) {
        sN[tid*20+16]=nb1[tid]; sN[tid*20+17]=nW2[2*tid]; sN[tid*20+18]=nW2[2*tid+1]; sN[tid*20+19]=0.f;
        sE[tid*12+8]=eb1[tid];  sE[tid*12+9]=eW2[2*tid];  sE[tid*12+10]=0.f; sE[tid*12+11]=0.f;
        sU[tid*12+6]=ub1[tid];  sU[tid*12+7]=uW2[2*tid];  sU[tid*12+8]=uW2[2*tid+1];
        sU[tid*12+9]=0.f; sU[tid*12+10]=0.f; sU[tid*12+11]=0.f;
    }
    if (tid < 96) sseg[tid] = 0.f;
    if (tid < 64) {
        // phi: wire-7 state for control pattern tid
        // bits 0..2 = wires 0,1,2 (CRY ctrl), bits 3..5 = wires 4,5,6 (CRX/CRZ ctrl)
        float cx = cosf(0.5f*inits[0]), sx = sinf(0.5f*inits[0]);
        float cy = cosf(0.5f*inits[1]), sy = sinf(0.5f*inits[1]);
        float cz = cosf(0.5f*inits[2]), sz = sinf(0.5f*inits[2]);
        float v0r = 1.f, v0i = 0.f, v1r = 0.f, v1i = 0.f;
        #pragma unroll
        for (int i = 0; i < 3; ++i) {
            int xb = (tid >> (3+i)) & 1;
            int yb = (tid >> i) & 1;
            if (xb) {
                float n0r = cx*v0r + sx*v1i, n0i = cx*v0i - sx*v1r;
                float n1r = sx*v0i + cx*v1r, n1i = -sx*v0r + cx*v1i;
                v0r=n0r; v0i=n0i; v1r=n1r; v1i=n1i;
            }
            if (yb) {
                float n0r = cy*v0r - sy*v1r, n0i = cy*v0i - sy*v1i;
                float n1r = sy*v0r + cy*v1r, n1i = sy*v0i + cy*v1i;
                v0r=n0r; v0i=n0i; v1r=n1r; v1i=n1i;
            }
            if (xb) {
                float n0r = cz*v0r + sz*v0i, n0i = cz*v0i - sz*v0r;
                float n1r = cz*v1r - sz*v1i, n1i = cz*v1i + sz*v1r;
                v0r=n0r; v0i=n0i; v1r=n1r; v1i=n1i;
            }
        }
        float4 g;
        g.x = v0r*v0r + v0i*v0i;
        g.y = v1r*v1r + v1i*v1i;
        g.z = v0r*v1r + v0i*v1i;   // Re(p0 p1*)
        g.w = v0i*v1r - v0r*v1i;   // Im(p0 p1*)
        sPhi[tid] = g;
    } else if (tid == 64) {
        // U = CNOT(7,3) CNOT(3,7) (Ra (x) Rb), basis idx = 2*w3 + w7; row perm {0,2,3,1}
        float Ra[2][2][2], Rb[2][2][2];
        rot2(update[0], update[1], update[2], Ra);
        rot2(update[3], update[4], update[5], Rb);
        const int src[4] = {0, 2, 3, 1};
        #pragma unroll
        for (int k = 0; k < 4; ++k) {
            int r = src[k], r3 = r >> 1, r7 = r & 1;
            #pragma unroll
            for (int c = 0; c < 4; ++c) {
                int c3 = c >> 1, c7 = c & 1;
                float ar = Ra[r3][c3][0], ai = Ra[r3][c3][1];
                float br = Rb[r7][c7][0], bi = Rb[r7][c7][1];
                sUm[(k*4+c)*2 + 0] = ar*br - ai*bi;
                sUm[(k*4+c)*2 + 1] = ar*bi + ai*br;
            }
        }
    }
    __syncthreads();

    const int half  = tid & 1;
    const int hbase = half << 6;           // this half's h-range start
    int n0 = blockIdx.x * 128 + (tid >> 1);
    bool valid = n0 < N;
    int nn = valid ? n0 : 0;

    const int4 sn = ((const int4*)sub_nodes)[nn];
    const int se0 = sub_edges[3*(size_t)nn+0];
    const int se1 = sub_edges[3*(size_t)nn+1];
    const int se2 = sub_edges[3*(size_t)nn+2];

    // ---- gather all inputs up front (hide latency under edge loop) ----
    const float4* ep0 = (const float4*)(edge_attr + (size_t)se0*8);
    const float4* ep1 = (const float4*)(edge_attr + (size_t)se1*8);
    const float4* ep2 = (const float4*)(edge_attr + (size_t)se2*8);
    float4 e0a=ep0[0], e0b=ep0[1], e1a=ep1[0], e1b=ep1[1], e2a=ep2[0], e2b=ep2[1];
    const float4* xp = (const float4*)(node_feat + (size_t)nn*16);
    float4 x0=xp[0], x1=xp[1], x2=xp[2], x3=xp[3];
    const float4* yp = (const float4*)(node_feat + (size_t)sn.y*16);
    float4 y0=yp[0], y1=yp[1], y2=yp[2], y3=yp[3];
    const float4* zp = (const float4*)(node_feat + (size_t)sn.z*16);
    float4 z0=zp[0], z1=zp[1], z2=zp[2], z3=zp[3];
    const float4* wp = (const float4*)(node_feat + (size_t)sn.w*16);
    float4 w0=wp[0], w1=wp[1], w2=wp[2], w3=wp[3];

    // ---- edge MLP x3 (a-col only), h split across the pair ----
    float aE0=0.f, aE1=0.f, aE2=0.f;
    #pragma unroll 4
    for (int j = 0; j < 64; ++j) {
        const float4* r = (const float4*)&sE[(j+hbase)*12];
        float4 f0=r[0], f1=r[1], f2=r[2];
        float t0=f2.x, t1=f2.x, t2=f2.x;
        t0=fmaf(e0a.x,f0.x,t0); t1=fmaf(e1a.x,f0.x,t1); t2=fmaf(e2a.x,f0.x,t2);
        t0=fmaf(e0a.y,f0.y,t0); t1=fmaf(e1a.y,f0.y,t1); t2=fmaf(e2a.y,f0.y,t2);
        t0=fmaf(e0a.z,f0.z,t0); t1=fmaf(e1a.z,f0.z,t1); t2=fmaf(e2a.z,f0.z,t2);
        t0=fmaf(e0a.w,f0.w,t0); t1=fmaf(e1a.w,f0.w,t1); t2=fmaf(e2a.w,f0.w,t2);
        t0=fmaf(e0b.x,f1.x,t0); t1=fmaf(e1b.x,f1.x,t1); t2=fmaf(e2b.x,f1.x,t2);
        t0=fmaf(e0b.y,f1.y,t0); t1=fmaf(e1b.y,f1.y,t1); t2=fmaf(e2b.y,f1.y,t2);
        t0=fmaf(e0b.z,f1.z,t0); t1=fmaf(e1b.z,f1.z,t1); t2=fmaf(e2b.z,f1.z,t2);
        t0=fmaf(e0b.w,f1.w,t0); t1=fmaf(e1b.w,f1.w,t1); t2=fmaf(e2b.w,f1.w,t2);
        float l0 = t0>0.f ? t0 : 0.01f*t0;
        float l1 = t1>0.f ? t1 : 0.01f*t1;
        float l2 = t2>0.f ? t2 : 0.01f*t2;
        aE0 = fmaf(l0, f2.y, aE0);
        aE1 = fmaf(l1, f2.y, aE1);
        aE2 = fmaf(l2, f2.y, aE2);
    }
    aE0 += __shfl_xor(aE0,1); aE1 += __shfl_xor(aE1,1); aE2 += __shfl_xor(aE2,1);

    // ---- node MLP: own (a,b) + 3 neighbors (a only), h split ----
    float aN0=0.f, aN1=0.f, aY=0.f, aZ=0.f, aWn=0.f;
    #pragma unroll 2
    for (int j = 0; j < 64; ++j) {
        const float4* r = (const float4*)&sN[(j+hbase)*20];
        float4 f0=r[0], f1=r[1], f2=r[2], f3=r[3], f4=r[4];
        float tx=f4.x, ty=f4.x, tz=f4.x, tw=f4.x;
        tx=fmaf(x0.x,f0.x,tx); ty=fmaf(y0.x,f0.x,ty); tz=fmaf(z0.x,f0.x,tz); tw=fmaf(w0.x,f0.x,tw);
        tx=fmaf(x0.y,f0.y,tx); ty=fmaf(y0.y,f0.y,ty); tz=fmaf(z0.y,f0.y,tz); tw=fmaf(w0.y,f0.y,tw);
        tx=fmaf(x0.z,f0.z,tx); ty=fmaf(y0.z,f0.z,ty); tz=fmaf(z0.z,f0.z,tz); tw=fmaf(w0.z,f0.z,tw);
        tx=fmaf(x0.w,f0.w,tx); ty=fmaf(y0.w,f0.w,ty); tz=fmaf(z0.w,f0.w,tz); tw=fmaf(w0.w,f0.w,tw);
        tx=fmaf(x1.x,f1.x,tx); ty=fmaf(y1.x,f1.x,ty); tz=fmaf(z1.x,f1.x,tz); tw=fmaf(w1.x,f1.x,tw);
        tx=fmaf(x1.y,f1.y,tx); ty=fmaf(y1.y,f1.y,ty); tz=fmaf(z1.y,f1.y,tz); tw=fmaf(w1.y,f1.y,tw);
        tx=fmaf(x1.z,f1.z,tx); ty=fmaf(y1.z,f1.z,ty); tz=fmaf(z1.z,f1.z,tz); tw=fmaf(w1.z,f1.z,tw);
        tx=fmaf(x1.w,f1.w,tx); ty=fmaf(y1.w,f1.w,ty); tz=fmaf(z1.w,f1.w,tz); tw=fmaf(w1.w,f1.w,tw);
        tx=fmaf(x2.x,f2.x,tx); ty=fmaf(y2.x,f2.x,ty); tz=fmaf(z2.x,f2.x,tz); tw=fmaf(w2.x,f2.x,tw);
        tx=fmaf(x2.y,f2.y,tx); ty=fmaf(y2.y,f2.y,ty); tz=fmaf(z2.y,f2.y,tz); tw=fmaf(w2.y,f2.y,tw);
        tx=fmaf(x2.z,f2.z,tx); ty=fmaf(y2.z,f2.z,ty); tz=fmaf(z2.z,f2.z,tz); tw=fmaf(w2.z,f2.z,tw);
        tx=fmaf(x2.w,f2.w,tx); ty=fmaf(y2.w,f2.w,ty); tz=fmaf(z2.w,f2.w,tz); tw=fmaf(w2.w,f2.w,tw);
        tx=fmaf(x3.x,f3.x,tx); ty=fmaf(y3.x,f3.x,ty); tz=fmaf(z3.x,f3.x,tz); tw=fmaf(w3.x,f3.x,tw);
        tx=fmaf(x3.y,f3.y,tx); ty=fmaf(y3.y,f3.y,ty); tz=fmaf(z3.y,f3.y,tz); tw=fmaf(w3.y,f3.y,tw);
        tx=fmaf(x3.z,f3.z,tx); ty=fmaf(y3.z,f3.z,ty); tz=fmaf(z3.z,f3.z,tz); tw=fmaf(w3.z,f3.z,tw);
        tx=fmaf(x3.w,f3.w,tx); ty=fmaf(y3.w,f3.w,ty); tz=fmaf(z3.w,f3.w,tz); tw=fmaf(w3.w,f3.w,tw);
        float lx = tx>0.f ? tx : 0.01f*tx;
        float ly = ty>0.f ? ty : 0.01f*ty;
        float lz = tz>0.f ? tz : 0.01f*tz;
        float lw = tw>0.f ? tw : 0.01f*tw;
        aN0 = fmaf(lx, f4.y, aN0); aN1 = fmaf(lx, f4.z, aN1);
        aY  = fmaf(ly, f4.y, aY);
        aZ  = fmaf(lz, f4.y, aZ);
        aWn = fmaf(lw, f4.y, aWn);
    }
    aN0 += __shfl_xor(aN0,1); aN1 += __shfl_xor(aN1,1);
    aY  += __shfl_xor(aY,1);  aZ  += __shfl_xor(aZ,1); aWn += __shfl_xor(aWn,1);

    float eb2_0 = eb2[0], nb2_0 = nb2[0], nb2_1 = nb2[1];
    float ae0 = tanhf(aE0 + eb2_0) * PI_F;
    float ae1 = tanhf(aE1 + eb2_0) * PI_F;
    float ae2 = tanhf(aE2 + eb2_0) * PI_F;
    float a3  = tanhf(aN0 + nb2_0) * PI_F;   // own a-angle (wire 3)
    float b3  = tanhf(aN1 + nb2_1) * PI_F;   // own b-angle
    float ay  = tanhf(aY  + nb2_0) * PI_F;
    float az  = tanhf(aZ  + nb2_0) * PI_F;
    float aw  = tanhf(aWn + nb2_0) * PI_F;

    // ---- circuit marginal: control weights cos^2(a/2) = (1+cos a)/2 ----
    float c0 = cosf(ae0), c1 = cosf(ae1), c2 = cosf(ae2);
    float d0 = cosf(ay),  d1 = cosf(az),  d2 = cosf(aw);
    float pe00=0.5f*(1.f+c0), pe01=0.5f*(1.f-c0);
    float pe10=0.5f*(1.f+c1), pe11=0.5f*(1.f-c1);
    float pe20=0.5f*(1.f+c2), pe21=0.5f*(1.f-c2);
    float pn00=0.5f*(1.f+d0), pn01=0.5f*(1.f-d0);
    float pn10=0.5f*(1.f+d1), pn11=0.5f*(1.f-d1);
    float pn20=0.5f*(1.f+d2), pn21=0.5f*(1.f-d2);
    float E[8], Nw[8];
    #pragma unroll
    for (int m = 0; m < 8; ++m) {
        E[m]  = ((m&1)?pe01:pe00) * ((m&2)?pe11:pe10) * ((m&4)?pe21:pe20);
        Nw[m] = ((m&1)?pn01:pn00) * ((m&2)?pn11:pn10) * ((m&4)?pn21:pn20);
    }
    float S0=0.f, S1=0.f, Sr=0.f, Si=0.f;
    #pragma unroll
    for (int q = 0; q < 4; ++q) {
        float Nq = half ? Nw[4+q] : Nw[q];
        #pragma unroll
        for (int p = 0; p < 8; ++p) {
            float W = E[p] * Nq;
            float4 g = sPhi[(half<<5) + q*8 + p];
            S0 = fmaf(W, g.x, S0); S1 = fmaf(W, g.y, S1);
            Sr = fmaf(W, g.z, Sr); Si = fmaf(W, g.w, Si);
        }
    }
    S0 += __shfl_xor(S0,1); S1 += __shfl_xor(S1,1);
    Sr += __shfl_xor(Sr,1); Si += __shfl_xor(Si,1);

    // center qubit + T = U (q3 (x) I) ; P[k]
    float ca = cosf(0.5f*a3), sa = sinf(0.5f*a3);
    float cb = cosf(0.5f*b3), sb = sinf(0.5f*b3);
    float q0r = ca*cb, q0i = -ca*sb, q1r = sa*cb, q1i = sa*sb;
    float P[4];
    #pragma unroll
    for (int k = 0; k < 4; ++k) {
        float u0r = sUm[(k*4+0)*2], u0i = sUm[(k*4+0)*2+1];
        float u1r = sUm[(k*4+2)*2], u1i = sUm[(k*4+2)*2+1];
        float T0r = u0r*q0r - u0i*q0i + u1r*q1r - u1i*q1i;
        float T0i = u0r*q0i + u0i*q0r + u1r*q1i + u1i*q1r;
        float w0r = sUm[(k*4+1)*2], w0i = sUm[(k*4+1)*2+1];
        float w1r = sUm[(k*4+3)*2], w1i = sUm[(k*4+3)*2+1];
        float T1r = w0r*q0r - w0i*q0i + w1r*q1r - w1i*q1i;
        float T1i = w0r*q0i + w0i*q0r + w1r*q1i + w1i*q1r;
        float Ar = T0r*T1r + T0i*T1i, Ai = T0i*T1r - T0r*T1i;
        P[k] = (T0r*T0r + T0i*T0i)*S0 + (T1r*T1r + T1i*T1i)*S1 + 2.f*(Ar*Sr - Ai*Si);
    }

    // ---- upd MLP (6->128->2), h split ----
    float u0 = 0.f, u1 = 0.f;
    #pragma unroll 4
    for (int j = 0; j < 64; ++j) {
        const float4* r = (const float4*)&sU[(j+hbase)*12];
        float4 f0=r[0], f1=r[1], f2=r[2];
        float t = f1.z;
        t = fmaf(a3,   f0.x, t); t = fmaf(b3,   f0.y, t);
        t = fmaf(P[0], f0.z, t); t = fmaf(P[1], f0.w, t);
        t = fmaf(P[2], f1.x, t); t = fmaf(P[3], f1.y, t);
        float lt = t > 0.f ? t : 0.01f*t;
        u0 = fmaf(lt, f1.w, u0);
        u1 = fmaf(lt, f2.x, u1);
    }
    u0 += __shfl_xor(u0,1); u1 += __shfl_xor(u1,1);

    // x = 1.5*nf + 0.5*upd (centers == arange(N)); LayerNorm over 2 features
    float x0v = 1.5f*a3 + 0.5f*(tanhf(u0 + ub2[0]) * PI_F);
    float x1v = 1.5f*b3 + 0.5f*(tanhf(u1 + ub2[1]) * PI_F);
    float mu  = 0.5f*(x0v + x1v);
    float dd  = x0v - mu;
    float inv = 1.0f / sqrtf(dd*dd + 1e-5f);
    float wv  = valid ? 1.f : 0.f;
    float xn0 = ( dd*inv*lng[0] + lnb[0]) * wv;
    float xn1 = (-dd*inv*lng[1] + lnb[1]) * wv;
    int bs = batch[nn];

    // ---- per-block segment partials (each node counted twice -> x0.5) ----
    bool uni = __all(bs == __shfl(bs, 0));
    if (uni) {
        float r0 = xn0, r1 = xn1, rc = wv;
        #pragma unroll
        for (int off = 32; off >= 1; off >>= 1) {
            r0 += __shfl_xor(r0, off); r1 += __shfl_xor(r1, off); rc += __shfl_xor(rc, off);
        }
        if ((tid & 63) == 0) {
            atomicAdd(&sseg[bs*3+0], 0.5f*r0);
            atomicAdd(&sseg[bs*3+1], 0.5f*r1);
            atomicAdd(&sseg[bs*3+2], 0.5f*rc);
        }
    } else if (valid && half == 0) {
        atomicAdd(&sseg[bs*3+0], xn0);
        atomicAdd(&sseg[bs*3+1], xn1);
        atomicAdd(&sseg[bs*3+2], 1.f);
    }
    __syncthreads();
    for (int idx = tid; idx < 96; idx += 256)
        part[(size_t)blockIdx.x*96 + idx] = sseg[idx];   // plain store, no init needed
}

// ---- k_head: reduce per-block partials + head MLP (2->2 leaky 2->2) ----
__global__ __launch_bounds__(128) void k_head(
    const float* __restrict__ part, int nb,
    const float* __restrict__ hW1, const float* __restrict__ hb1,
    const float* __restrict__ hW2, const float* __restrict__ hb2,
    float* __restrict__ out)
{
    __shared__ float tot[96];
    int t = threadIdx.x;
    if (t < 96) {
        float s = 0.f;
        for (int b = 0; b < nb; ++b) s += part[(size_t)b*96 + t];
        tot[t] = s;
    }
    __syncthreads();
    if (t < 32) {
        float c  = tot[t*3+2];
        float iv = c > 0.f ? 1.f/c : 0.f;
        float g0 = tot[t*3+0]*iv, g1 = tot[t*3+1]*iv;
        float a = hb1[0] + g0*hW1[0] + g1*hW1[2];
        float b = hb1[1] + g0*hW1[1] + g1*hW1[3];
        float h0 = a > 0.f ? a : 0.01f*a;
        float h1 = b > 0.f ? b : 0.01f*b;
        out[t*2+0] = hb2[0] + h0*hW2[0] + h1*hW2[2];
        out[t*2+1] = hb2[1] + h0*hW2[1] + h1*hW2[3];
    }
}

extern "C" void kernel_launch(void* const* d_in, const int* in_sizes, int n_in,
                              void* d_out, int out_size, void* d_ws, size_t ws_size,
                              hipStream_t stream)
{
    const float* node_feat = (const float*)d_in[0];
    const float* edge_attr = (const float*)d_in[1];
    const float* node_W1 = (const float*)d_in[2];
    const float* node_b1 = (const float*)d_in[3];
    const float* node_W2 = (const float*)d_in[4];
    const float* node_b2 = (const float*)d_in[5];
    const float* edge_W1 = (const float*)d_in[6];
    const float* edge_b1 = (const float*)d_in[7];
    const float* edge_W2 = (const float*)d_in[8];
    const float* edge_b2 = (const float*)d_in[9];
    const float* inits   = (const float*)d_in[10];
    const float* update  = (const float*)d_in[11];
    const float* upd_W1  = (const float*)d_in[12];
    const float* upd_b1  = (const float*)d_in[13];
    const float* upd_W2  = (const float*)d_in[14];
    const float* upd_b2  = (const float*)d_in[15];
    const float* ln_g    = (const float*)d_in[16];
    const float* ln_b    = (const float*)d_in[17];
    const float* head_W1 = (const float*)d_in[18];
    const float* head_b1 = (const float*)d_in[19];
    const float* head_W2 = (const float*)d_in[20];
    const float* head_b2 = (const float*)d_in[21];
    const int* sub_nodes = (const int*)d_in[22];
    const int* sub_edges = (const int*)d_in[23];
    const int* batch     = (const int*)d_in[24];

    int N = in_sizes[24];            // 32768
    int nb = (N + 127) / 128;        // 256 blocks

    float* part = (float*)d_ws;
    if (ws_size < (size_t)nb * 96 * sizeof(float)) return;

    k_all<<<nb, 256, 0, stream>>>(node_feat, edge_attr,
        node_W1, node_b1, node_W2, node_b2,
        edge_W1, edge_b1, edge_W2, edge_b2,
        upd_W1, upd_b1, upd_W2, upd_b2,
        inits, update, ln_g, ln_b,
        sub_nodes, sub_edges, batch,
        part, N);
    k_head<<<1, 128, 0, stream>>>(part, nb,
        head_W1, head_b1, head_W2, head_b2, (float*)d_out);
}

// Round 9
// 58.883 us; speedup vs baseline: 1.5069x; 1.5069x over previous
//
#include <hip/hip_runtime.h>
#include <math.h>

static constexpr float PI_F = 3.14159265358979323846f;

// ws: per-block segment partials, layout part[g * nb + b], g in [0,96), b in [0,nb).
// Plain stores only -> no initialization needed (poison-immune).

__device__ inline void rot2(float p, float t, float o, float R[2][2][2]) {
    // Rot(p,t,o) = Rz(o) Ry(t) Rz(p)
    float ct = cosf(0.5f*t), st = sinf(0.5f*t);
    float apo = 0.5f*(p+o), amo = 0.5f*(p-o);
    R[0][0][0] =  ct*cosf(apo); R[0][0][1] = -ct*sinf(apo);
    R[0][1][0] = -st*cosf(amo); R[0][1][1] = -st*sinf(amo);
    R[1][0][0] =  st*cosf(amo); R[1][0][1] = -st*sinf(amo);
    R[1][1][0] =  ct*cosf(apo); R[1][1][1] =  ct*sinf(apo);
}

// Fused kernel: 256 thr/block, 64 nodes/block, 4 threads/node (h quarter-split, interleaved).
__global__ __launch_bounds__(256, 2) void k_all(
    const float* __restrict__ node_feat, const float* __restrict__ edge_attr,
    const float* __restrict__ nW1, const float* __restrict__ nb1,
    const float* __restrict__ nW2, const float* __restrict__ nb2,
    const float* __restrict__ eW1, const float* __restrict__ eb1,
    const float* __restrict__ eW2, const float* __restrict__ eb2,
    const float* __restrict__ uW1, const float* __restrict__ ub1,
    const float* __restrict__ uW2, const float* __restrict__ ub2,
    const float* __restrict__ inits, const float* __restrict__ update,
    const float* __restrict__ lng, const float* __restrict__ lnb,
    const int* __restrict__ sub_nodes, const int* __restrict__ sub_edges,
    const int* __restrict__ batch,
    float* __restrict__ part, int N, int nb)
{
    __shared__ __align__(16) float sN[128*20]; // {W1t[0..15], b1, w2a, w2b, pad}
    __shared__ __align__(16) float sE[128*12]; // {W1t[0..7], b1, w2a, pad, pad}
    __shared__ __align__(16) float sU[128*12]; // {W1t[0..5], b1, w2a, w2b, pad x3}
    __shared__ float4 sPhi[64];
    __shared__ float  sUm[32];
    __shared__ float  sseg[96];
    const int tid = threadIdx.x;

    // ---- stage weights (coalesced global reads, transposed packed rows) ----
    for (int idx = tid; idx < 2048; idx += 256) sN[(idx&127)*20 + (idx>>7)] = nW1[idx];
    for (int idx = tid; idx < 1024; idx += 256) sE[(idx&127)*12 + (idx>>7)] = eW1[idx];
    for (int idx = tid; idx < 768;  idx += 256) sU[(idx&127)*12 + (idx>>7)] = uW1[idx];
    if (tid < 128) {
        sN[tid*20+16]=nb1[tid]; sN[tid*20+17]=nW2[2*tid]; sN[tid*20+18]=nW2[2*tid+1]; sN[tid*20+19]=0.f;
        sE[tid*12+8]=eb1[tid];  sE[tid*12+9]=eW2[2*tid];  sE[tid*12+10]=0.f; sE[tid*12+11]=0.f;
        sU[tid*12+6]=ub1[tid];  sU[tid*12+7]=uW2[2*tid];  sU[tid*12+8]=uW2[2*tid+1];
        sU[tid*12+9]=0.f; sU[tid*12+10]=0.f; sU[tid*12+11]=0.f;
    }
    if (tid < 96) sseg[tid] = 0.f;
    if (tid < 64) {
        // phi: wire-7 state for control pattern tid
        // bits 0..2 = wires 0,1,2 (CRY ctrl), bits 3..5 = wires 4,5,6 (CRX/CRZ ctrl)
        float cx = cosf(0.5f*inits[0]), sx = sinf(0.5f*inits[0]);
        float cy = cosf(0.5f*inits[1]), sy = sinf(0.5f*inits[1]);
        float cz = cosf(0.5f*inits[2]), sz = sinf(0.5f*inits[2]);
        float v0r = 1.f, v0i = 0.f, v1r = 0.f, v1i = 0.f;
        #pragma unroll
        for (int i = 0; i < 3; ++i) {
            int xb = (tid >> (3+i)) & 1;
            int yb = (tid >> i) & 1;
            if (xb) {
                float n0r = cx*v0r + sx*v1i, n0i = cx*v0i - sx*v1r;
                float n1r = sx*v0i + cx*v1r, n1i = -sx*v0r + cx*v1i;
                v0r=n0r; v0i=n0i; v1r=n1r; v1i=n1i;
            }
            if (yb) {
                float n0r = cy*v0r - sy*v1r, n0i = cy*v0i - sy*v1i;
                float n1r = sy*v0r + cy*v1r, n1i = sy*v0i + cy*v1i;
                v0r=n0r; v0i=n0i; v1r=n1r; v1i=n1i;
            }
            if (xb) {
                float n0r = cz*v0r + sz*v0i, n0i = cz*v0i - sz*v0r;
                float n1r = cz*v1r - sz*v1i, n1i = cz*v1i + sz*v1r;
                v0r=n0r; v0i=n0i; v1r=n1r; v1i=n1i;
            }
        }
        float4 g;
        g.x = v0r*v0r + v0i*v0i;
        g.y = v1r*v1r + v1i*v1i;
        g.z = v0r*v1r + v0i*v1i;   // Re(p0 p1*)
        g.w = v0i*v1r - v0r*v1i;   // Im(p0 p1*)
        sPhi[tid] = g;
    } else if (tid == 64) {
        // U = CNOT(7,3) CNOT(3,7) (Ra (x) Rb), basis idx = 2*w3 + w7; row perm {0,2,3,1}
        float Ra[2][2][2], Rb[2][2][2];
        rot2(update[0], update[1], update[2], Ra);
        rot2(update[3], update[4], update[5], Rb);
        const int src[4] = {0, 2, 3, 1};
        #pragma unroll
        for (int k = 0; k < 4; ++k) {
            int r = src[k], r3 = r >> 1, r7 = r & 1;
            #pragma unroll
            for (int c = 0; c < 4; ++c) {
                int c3 = c >> 1, c7 = c & 1;
                float ar = Ra[r3][c3][0], ai = Ra[r3][c3][1];
                float br = Rb[r7][c7][0], bi = Rb[r7][c7][1];
                sUm[(k*4+c)*2 + 0] = ar*br - ai*bi;
                sUm[(k*4+c)*2 + 1] = ar*bi + ai*br;
            }
        }
    }
    __syncthreads();

    const int quarter = tid & 3;           // h = 4*j + quarter (interleaved: bank-conflict-free)
    int n0 = blockIdx.x * 64 + (tid >> 2);
    bool valid = n0 < N;
    int nn = valid ? n0 : 0;

    const int4 sn = ((const int4*)sub_nodes)[nn];
    const int se0 = sub_edges[3*(size_t)nn+0];
    const int se1 = sub_edges[3*(size_t)nn+1];
    const int se2 = sub_edges[3*(size_t)nn+2];

    // ---- gather all inputs up front ----
    const float4* ep0 = (const float4*)(edge_attr + (size_t)se0*8);
    const float4* ep1 = (const float4*)(edge_attr + (size_t)se1*8);
    const float4* ep2 = (const float4*)(edge_attr + (size_t)se2*8);
    float4 e0a=ep0[0], e0b=ep0[1], e1a=ep1[0], e1b=ep1[1], e2a=ep2[0], e2b=ep2[1];
    const float4* xp = (const float4*)(node_feat + (size_t)nn*16);
    float4 x0=xp[0], x1=xp[1], x2=xp[2], x3=xp[3];
    const float4* yp = (const float4*)(node_feat + (size_t)sn.y*16);
    float4 y0=yp[0], y1=yp[1], y2=yp[2], y3=yp[3];
    const float4* zp = (const float4*)(node_feat + (size_t)sn.z*16);
    float4 z0=zp[0], z1=zp[1], z2=zp[2], z3=zp[3];
    const float4* wp = (const float4*)(node_feat + (size_t)sn.w*16);
    float4 w0=wp[0], w1=wp[1], w2=wp[2], w3=wp[3];

    // ---- edge MLP x3 (a-col only), h quarter-split ----
    float aE0=0.f, aE1=0.f, aE2=0.f;
    #pragma unroll 4
    for (int j = 0; j < 32; ++j) {
        const float4* r = (const float4*)&sE[(4*j + quarter)*12];
        float4 f0=r[0], f1=r[1], f2=r[2];
        float t0=f2.x, t1=f2.x, t2=f2.x;
        t0=fmaf(e0a.x,f0.x,t0); t1=fmaf(e1a.x,f0.x,t1); t2=fmaf(e2a.x,f0.x,t2);
        t0=fmaf(e0a.y,f0.y,t0); t1=fmaf(e1a.y,f0.y,t1); t2=fmaf(e2a.y,f0.y,t2);
        t0=fmaf(e0a.z,f0.z,t0); t1=fmaf(e1a.z,f0.z,t1); t2=fmaf(e2a.z,f0.z,t2);
        t0=fmaf(e0a.w,f0.w,t0); t1=fmaf(e1a.w,f0.w,t1); t2=fmaf(e2a.w,f0.w,t2);
        t0=fmaf(e0b.x,f1.x,t0); t1=fmaf(e1b.x,f1.x,t1); t2=fmaf(e2b.x,f1.x,t2);
        t0=fmaf(e0b.y,f1.y,t0); t1=fmaf(e1b.y,f1.y,t1); t2=fmaf(e2b.y,f1.y,t2);
        t0=fmaf(e0b.z,f1.z,t0); t1=fmaf(e1b.z,f1.z,t1); t2=fmaf(e2b.z,f1.z,t2);
        t0=fmaf(e0b.w,f1.w,t0); t1=fmaf(e1b.w,f1.w,t1); t2=fmaf(e2b.w,f1.w,t2);
        float l0 = t0>0.f ? t0 : 0.01f*t0;
        float l1 = t1>0.f ? t1 : 0.01f*t1;
        float l2 = t2>0.f ? t2 : 0.01f*t2;
        aE0 = fmaf(l0, f2.y, aE0);
        aE1 = fmaf(l1, f2.y, aE1);
        aE2 = fmaf(l2, f2.y, aE2);
    }
    aE0 += __shfl_xor(aE0,1); aE0 += __shfl_xor(aE0,2);
    aE1 += __shfl_xor(aE1,1); aE1 += __shfl_xor(aE1,2);
    aE2 += __shfl_xor(aE2,1); aE2 += __shfl_xor(aE2,2);

    // ---- node MLP: own (a,b) + 3 neighbors (a only), h quarter-split ----
    float aN0=0.f, aN1=0.f, aY=0.f, aZ=0.f, aWn=0.f;
    #pragma unroll 2
    for (int j = 0; j < 32; ++j) {
        const float4* r = (const float4*)&sN[(4*j + quarter)*20];
        float4 f0=r[0], f1=r[1], f2=r[2], f3=r[3], f4=r[4];
        float tx=f4.x, ty=f4.x, tz=f4.x, tw=f4.x;
        tx=fmaf(x0.x,f0.x,tx); ty=fmaf(y0.x,f0.x,ty); tz=fmaf(z0.x,f0.x,tz); tw=fmaf(w0.x,f0.x,tw);
        tx=fmaf(x0.y,f0.y,tx); ty=fmaf(y0.y,f0.y,ty); tz=fmaf(z0.y,f0.y,tz); tw=fmaf(w0.y,f0.y,tw);
        tx=fmaf(x0.z,f0.z,tx); ty=fmaf(y0.z,f0.z,ty); tz=fmaf(z0.z,f0.z,tz); tw=fmaf(w0.z,f0.z,tw);
        tx=fmaf(x0.w,f0.w,tx); ty=fmaf(y0.w,f0.w,ty); tz=fmaf(z0.w,f0.w,tz); tw=fmaf(w0.w,f0.w,tw);
        tx=fmaf(x1.x,f1.x,tx); ty=fmaf(y1.x,f1.x,ty); tz=fmaf(z1.x,f1.x,tz); tw=fmaf(w1.x,f1.x,tw);
        tx=fmaf(x1.y,f1.y,tx); ty=fmaf(y1.y,f1.y,ty); tz=fmaf(z1.y,f1.y,tz); tw=fmaf(w1.y,f1.y,tw);
        tx=fmaf(x1.z,f1.z,tx); ty=fmaf(y1.z,f1.z,ty); tz=fmaf(z1.z,f1.z,tz); tw=fmaf(w1.z,f1.z,tw);
        tx=fmaf(x1.w,f1.w,tx); ty=fmaf(y1.w,f1.w,ty); tz=fmaf(z1.w,f1.w,tz); tw=fmaf(w1.w,f1.w,tw);
        tx=fmaf(x2.x,f2.x,tx); ty=fmaf(y2.x,f2.x,ty); tz=fmaf(z2.x,f2.x,tz); tw=fmaf(w2.x,f2.x,tw);
        tx=fmaf(x2.y,f2.y,tx); ty=fmaf(y2.y,f2.y,ty); tz=fmaf(z2.y,f2.y,tz); tw=fmaf(w2.y,f2.y,tw);
        tx=fmaf(x2.z,f2.z,tx); ty=fmaf(y2.z,f2.z,ty); tz=fmaf(z2.z,f2.z,tz); tw=fmaf(w2.z,f2.z,tw);
        tx=fmaf(x2.w,f2.w,tx); ty=fmaf(y2.w,f2.w,ty); tz=fmaf(z2.w,f2.w,tz); tw=fmaf(w2.w,f2.w,tw);
        tx=fmaf(x3.x,f3.x,tx); ty=fmaf(y3.x,f3.x,ty); tz=fmaf(z3.x,f3.x,tz); tw=fmaf(w3.x,f3.x,tw);
        tx=fmaf(x3.y,f3.y,tx); ty=fmaf(y3.y,f3.y,ty); tz=fmaf(z3.y,f3.y,tz); tw=fmaf(w3.y,f3.y,tw);
        tx=fmaf(x3.z,f3.z,tx); ty=fmaf(y3.z,f3.z,ty); tz=fmaf(z3.z,f3.z,tz); tw=fmaf(w3.z,f3.z,tw);
        tx=fmaf(x3.w,f3.w,tx); ty=fmaf(y3.w,f3.w,ty); tz=fmaf(z3.w,f3.w,tz); tw=fmaf(w3.w,f3.w,tw);
        float lx = tx>0.f ? tx : 0.01f*tx;
        float ly = ty>0.f ? ty : 0.01f*ty;
        float lz = tz>0.f ? tz : 0.01f*tz;
        float lw = tw>0.f ? tw : 0.01f*tw;
        aN0 = fmaf(lx, f4.y, aN0); aN1 = fmaf(lx, f4.z, aN1);
        aY  = fmaf(ly, f4.y, aY);
        aZ  = fmaf(lz, f4.y, aZ);
        aWn = fmaf(lw, f4.y, aWn);
    }
    aN0 += __shfl_xor(aN0,1); aN0 += __shfl_xor(aN0,2);
    aN1 += __shfl_xor(aN1,1); aN1 += __shfl_xor(aN1,2);
    aY  += __shfl_xor(aY,1);  aY  += __shfl_xor(aY,2);
    aZ  += __shfl_xor(aZ,1);  aZ  += __shfl_xor(aZ,2);
    aWn += __shfl_xor(aWn,1); aWn += __shfl_xor(aWn,2);

    float eb2_0 = eb2[0], nb2_0 = nb2[0], nb2_1 = nb2[1];
    float ae0 = tanhf(aE0 + eb2_0) * PI_F;
    float ae1 = tanhf(aE1 + eb2_0) * PI_F;
    float ae2 = tanhf(aE2 + eb2_0) * PI_F;
    float a3  = tanhf(aN0 + nb2_0) * PI_F;   // own a-angle (wire 3)
    float b3  = tanhf(aN1 + nb2_1) * PI_F;   // own b-angle
    float ay  = tanhf(aY  + nb2_0) * PI_F;
    float az  = tanhf(aZ  + nb2_0) * PI_F;
    float aw  = tanhf(aWn + nb2_0) * PI_F;

    // ---- circuit marginal: control weights cos^2(a/2) = (1+cos a)/2 ----
    float c0 = cosf(ae0), c1 = cosf(ae1), c2 = cosf(ae2);
    float d0 = cosf(ay),  d1 = cosf(az),  d2 = cosf(aw);
    float pe00=0.5f*(1.f+c0), pe01=0.5f*(1.f-c0);
    float pe10=0.5f*(1.f+c1), pe11=0.5f*(1.f-c1);
    float pe20=0.5f*(1.f+c2), pe21=0.5f*(1.f-c2);
    float pn00=0.5f*(1.f+d0), pn01=0.5f*(1.f-d0);
    float pn10=0.5f*(1.f+d1), pn11=0.5f*(1.f-d1);
    float pn20=0.5f*(1.f+d2), pn21=0.5f*(1.f-d2);
    float E[8], Nw[8];
    #pragma unroll
    for (int m = 0; m < 8; ++m) {
        E[m]  = ((m&1)?pe01:pe00) * ((m&2)?pe11:pe10) * ((m&4)?pe21:pe20);
        Nw[m] = ((m&1)?pn01:pn00) * ((m&2)?pn11:pn10) * ((m&4)?pn21:pn20);
    }
    // S-sum over 64 patterns, 16 per thread (interleaved m = 4*j + quarter)
    float S0=0.f, S1=0.f, Sr=0.f, Si=0.f;
    #pragma unroll
    for (int j = 0; j < 16; ++j) {
        int m = 4*j + quarter;
        float W = E[m & 7] * Nw[m >> 3];
        float4 g = sPhi[m];
        S0 = fmaf(W, g.x, S0); S1 = fmaf(W, g.y, S1);
        Sr = fmaf(W, g.z, Sr); Si = fmaf(W, g.w, Si);
    }
    S0 += __shfl_xor(S0,1); S0 += __shfl_xor(S0,2);
    S1 += __shfl_xor(S1,1); S1 += __shfl_xor(S1,2);
    Sr += __shfl_xor(Sr,1); Sr += __shfl_xor(Sr,2);
    Si += __shfl_xor(Si,1); Si += __shfl_xor(Si,2);

    // center qubit + T = U (q3 (x) I) ; P[k]
    float ca = cosf(0.5f*a3), sa = sinf(0.5f*a3);
    float cb = cosf(0.5f*b3), sb = sinf(0.5f*b3);
    float q0r = ca*cb, q0i = -ca*sb, q1r = sa*cb, q1i = sa*sb;
    float P[4];
    #pragma unroll
    for (int k = 0; k < 4; ++k) {
        float u0r = sUm[(k*4+0)*2], u0i = sUm[(k*4+0)*2+1];
        float u1r = sUm[(k*4+2)*2], u1i = sUm[(k*4+2)*2+1];
        float T0r = u0r*q0r - u0i*q0i + u1r*q1r - u1i*q1i;
        float T0i = u0r*q0i + u0i*q0r + u1r*q1i + u1i*q1r;
        float w0r = sUm[(k*4+1)*2], w0i = sUm[(k*4+1)*2+1];
        float w1r = sUm[(k*4+3)*2], w1i = sUm[(k*4+3)*2+1];
        float T1r = w0r*q0r - w0i*q0i + w1r*q1r - w1i*q1i;
        float T1i = w0r*q0i + w0i*q0r + w1r*q1i + w1i*q1r;
        float Ar = T0r*T1r + T0i*T1i, Ai = T0i*T1r - T0r*T1i;
        P[k] = (T0r*T0r + T0i*T0i)*S0 + (T1r*T1r + T1i*T1i)*S1 + 2.f*(Ar*Sr - Ai*Si);
    }

    // ---- upd MLP (6->128->2), h quarter-split ----
    float u0 = 0.f, u1 = 0.f;
    #pragma unroll 4
    for (int j = 0; j < 32; ++j) {
        const float4* r = (const float4*)&sU[(4*j + quarter)*12];
        float4 f0=r[0], f1=r[1], f2=r[2];
        float t = f1.z;
        t = fmaf(a3,   f0.x, t); t = fmaf(b3,   f0.y, t);
        t = fmaf(P[0], f0.z, t); t = fmaf(P[1], f0.w, t);
        t = fmaf(P[2], f1.x, t); t = fmaf(P[3], f1.y, t);
        float lt = t > 0.f ? t : 0.01f*t;
        u0 = fmaf(lt, f1.w, u0);
        u1 = fmaf(lt, f2.x, u1);
    }
    u0 += __shfl_xor(u0,1); u0 += __shfl_xor(u0,2);
    u1 += __shfl_xor(u1,1); u1 += __shfl_xor(u1,2);

    // x = 1.5*nf + 0.5*upd (centers == arange(N)); LayerNorm over 2 features
    float x0v = 1.5f*a3 + 0.5f*(tanhf(u0 + ub2[0]) * PI_F);
    float x1v = 1.5f*b3 + 0.5f*(tanhf(u1 + ub2[1]) * PI_F);
    float mu  = 0.5f*(x0v + x1v);
    float dd  = x0v - mu;
    float inv = 1.0f / sqrtf(dd*dd + 1e-5f);
    float wv  = valid ? 1.f : 0.f;
    float xn0 = ( dd*inv*lng[0] + lnb[0]) * wv;
    float xn1 = (-dd*inv*lng[1] + lnb[1]) * wv;
    int bs = batch[nn];

    // ---- per-block segment partials (each node counted 4x -> x0.25) ----
    bool uni = __all(bs == __shfl(bs, 0));
    if (uni) {
        float r0 = xn0, r1 = xn1, rc = wv;
        #pragma unroll
        for (int off = 32; off >= 1; off >>= 1) {
            r0 += __shfl_xor(r0, off); r1 += __shfl_xor(r1, off); rc += __shfl_xor(rc, off);
        }
        if ((tid & 63) == 0) {
            atomicAdd(&sseg[bs*3+0], 0.25f*r0);
            atomicAdd(&sseg[bs*3+1], 0.25f*r1);
            atomicAdd(&sseg[bs*3+2], 0.25f*rc);
        }
    } else if (valid && quarter == 0) {
        atomicAdd(&sseg[bs*3+0], xn0);
        atomicAdd(&sseg[bs*3+1], xn1);
        atomicAdd(&sseg[bs*3+2], 1.f);
    }
    __syncthreads();
    for (int idx = tid; idx < 96; idx += 256)
        part[(size_t)idx * nb + blockIdx.x] = sseg[idx];   // plain store, no init needed
}

// ---- k_head: parallel reduce of per-block partials + head MLP (2->2 leaky 2->2) ----
__global__ __launch_bounds__(256) void k_head(
    const float* __restrict__ part, int nb,
    const float* __restrict__ hW1, const float* __restrict__ hb1,
    const float* __restrict__ hW2, const float* __restrict__ hb2,
    float* __restrict__ out)
{
    __shared__ float tot[96];
    const int tid  = threadIdx.x;
    const int wave = tid >> 6;      // 4 waves, 24 rows each
    const int lane = tid & 63;

    float acc[24];
    #pragma unroll
    for (int rr = 0; rr < 24; ++rr) acc[rr] = 0.f;
    for (int c = lane; c < nb; c += 64) {
        #pragma unroll
        for (int rr = 0; rr < 24; ++rr)
            acc[rr] += part[(size_t)(wave*24 + rr) * nb + c];   // 24 independent loads in flight
    }
    #pragma unroll
    for (int rr = 0; rr < 24; ++rr) {
        float s = acc[rr];
        #pragma unroll
        for (int off = 32; off >= 1; off >>= 1) s += __shfl_xor(s, off);
        if (lane == 0) tot[wave*24 + rr] = s;
    }
    __syncthreads();
    if (tid < 32) {
        float c  = tot[tid*3+2];
        float iv = c > 0.f ? 1.f/c : 0.f;
        float g0 = tot[tid*3+0]*iv, g1 = tot[tid*3+1]*iv;
        float a = hb1[0] + g0*hW1[0] + g1*hW1[2];
        float b = hb1[1] + g0*hW1[1] + g1*hW1[3];
        float h0 = a > 0.f ? a : 0.01f*a;
        float h1 = b > 0.f ? b : 0.01f*b;
        out[tid*2+0] = hb2[0] + h0*hW2[0] + h1*hW2[2];
        out[tid*2+1] = hb2[1] + h0*hW2[1] + h1*hW2[3];
    }
}

extern "C" void kernel_launch(void* const* d_in, const int* in_sizes, int n_in,
                              void* d_out, int out_size, void* d_ws, size_t ws_size,
                              hipStream_t stream)
{
    const float* node_feat = (const float*)d_in[0];
    const float* edge_attr = (const float*)d_in[1];
    const float* node_W1 = (const float*)d_in[2];
    const float* node_b1 = (const float*)d_in[3];
    const float* node_W2 = (const float*)d_in[4];
    const float* node_b2 = (const float*)d_in[5];
    const float* edge_W1 = (const float*)d_in[6];
    const float* edge_b1 = (const float*)d_in[7];
    const float* edge_W2 = (const float*)d_in[8];
    const float* edge_b2 = (const float*)d_in[9];
    const float* inits   = (const float*)d_in[10];
    const float* update  = (const float*)d_in[11];
    const float* upd_W1  = (const float*)d_in[12];
    const float* upd_b1  = (const float*)d_in[13];
    const float* upd_W2  = (const float*)d_in[14];
    const float* upd_b2  = (const float*)d_in[15];
    const float* ln_g    = (const float*)d_in[16];
    const float* ln_b    = (const float*)d_in[17];
    const float* head_W1 = (const float*)d_in[18];
    const float* head_b1 = (const float*)d_in[19];
    const float* head_W2 = (const float*)d_in[20];
    const float* head_b2 = (const float*)d_in[21];
    const int* sub_nodes = (const int*)d_in[22];
    const int* sub_edges = (const int*)d_in[23];
    const int* batch     = (const int*)d_in[24];

    int N  = in_sizes[24];           // 32768
    int nb = (N + 63) / 64;          // 512 blocks

    float* part = (float*)d_ws;
    if (ws_size < (size_t)nb * 96 * sizeof(float)) return;

    k_all<<<nb, 256, 0, stream>>>(node_feat, edge_attr,
        node_W1, node_b1, node_W2, node_b2,
        edge_W1, edge_b1, edge_W2, edge_b2,
        upd_W1, upd_b1, upd_W2, upd_b2,
        inits, update, ln_g, ln_b,
        sub_nodes, sub_edges, batch,
        part, N, nb);
    k_head<<<1, 256, 0, stream>>>(part, nb,
        head_W1, head_b1, head_W2, head_b2, (float*)d_out);
}

// Round 10
// 52.556 us; speedup vs baseline: 1.6883x; 1.1204x over previous
//
#include <hip/hip_runtime.h>
#include <math.h>

static constexpr float PI_F = 3.14159265358979323846f;

// ws: per-block segment partials, layout part[g * nb + b], g in [0,96), b in [0,nb).
// Plain stores only -> no initialization needed (poison-immune).

__device__ inline void rot2(float p, float t, float o, float R[2][2][2]) {
    // Rot(p,t,o) = Rz(o) Ry(t) Rz(p)
    float ct = cosf(0.5f*t), st = sinf(0.5f*t);
    float apo = 0.5f*(p+o), amo = 0.5f*(p-o);
    R[0][0][0] =  ct*cosf(apo); R[0][0][1] = -ct*sinf(apo);
    R[0][1][0] = -st*cosf(amo); R[0][1][1] = -st*sinf(amo);
    R[1][0][0] =  st*cosf(amo); R[1][0][1] = -st*sinf(amo);
    R[1][1][0] =  ct*cosf(apo); R[1][1][1] =  ct*sinf(apo);
}

// Fused kernel (R8 structure, measured 25.8us): 256 thr/block, 128 nodes/block,
// 2 threads/node (h half-split). NO tight launch_bounds: let the allocator use
// the VGPRs it needs (R9's (256,2) cap caused scratch spills -> 2.2x regression).
__global__ __launch_bounds__(256, 1) void k_all(
    const float* __restrict__ node_feat, const float* __restrict__ edge_attr,
    const float* __restrict__ nW1, const float* __restrict__ nb1,
    const float* __restrict__ nW2, const float* __restrict__ nb2,
    const float* __restrict__ eW1, const float* __restrict__ eb1,
    const float* __restrict__ eW2, const float* __restrict__ eb2,
    const float* __restrict__ uW1, const float* __restrict__ ub1,
    const float* __restrict__ uW2, const float* __restrict__ ub2,
    const float* __restrict__ inits, const float* __restrict__ update,
    const float* __restrict__ lng, const float* __restrict__ lnb,
    const int* __restrict__ sub_nodes, const int* __restrict__ sub_edges,
    const int* __restrict__ batch,
    float* __restrict__ part, int N, int nb)
{
    __shared__ __align__(16) float sN[128*20]; // {W1t[0..15], b1, w2a, w2b, pad}
    __shared__ __align__(16) float sE[128*12]; // {W1t[0..7], b1, w2a, pad, pad}
    __shared__ __align__(16) float sU[128*12]; // {W1t[0..5], b1, w2a, w2b, pad x3}
    __shared__ float4 sPhi[64];
    __shared__ float  sUm[32];
    __shared__ float  sseg[96];
    const int tid = threadIdx.x;

    // ---- stage weights (coalesced global reads, transposed packed rows) ----
    for (int idx = tid; idx < 2048; idx += 256) sN[(idx&127)*20 + (idx>>7)] = nW1[idx];
    for (int idx = tid; idx < 1024; idx += 256) sE[(idx&127)*12 + (idx>>7)] = eW1[idx];
    for (int idx = tid; idx < 768;  idx += 256) sU[(idx&127)*12 + (idx>>7)] = uW1[idx];
    if (tid < 128) {
        sN[tid*20+16]=nb1[tid]; sN[tid*20+17]=nW2[2*tid]; sN[tid*20+18]=nW2[2*tid+1]; sN[tid*20+19]=0.f;
        sE[tid*12+8]=eb1[tid];  sE[tid*12+9]=eW2[2*tid];  sE[tid*12+10]=0.f; sE[tid*12+11]=0.f;
        sU[tid*12+6]=ub1[tid];  sU[tid*12+7]=uW2[2*tid];  sU[tid*12+8]=uW2[2*tid+1];
        sU[tid*12+9]=0.f; sU[tid*12+10]=0.f; sU[tid*12+11]=0.f;
    }
    if (tid < 96) sseg[tid] = 0.f;
    if (tid < 64) {
        // phi: wire-7 state for control pattern tid
        // bits 0..2 = wires 0,1,2 (CRY ctrl), bits 3..5 = wires 4,5,6 (CRX/CRZ ctrl)
        float cx = cosf(0.5f*inits[0]), sx = sinf(0.5f*inits[0]);
        float cy = cosf(0.5f*inits[1]), sy = sinf(0.5f*inits[1]);
        float cz = cosf(0.5f*inits[2]), sz = sinf(0.5f*inits[2]);
        float v0r = 1.f, v0i = 0.f, v1r = 0.f, v1i = 0.f;
        #pragma unroll
        for (int i = 0; i < 3; ++i) {
            int xb = (tid >> (3+i)) & 1;
            int yb = (tid >> i) & 1;
            if (xb) {
                float n0r = cx*v0r + sx*v1i, n0i = cx*v0i - sx*v1r;
                float n1r = sx*v0i + cx*v1r, n1i = -sx*v0r + cx*v1i;
                v0r=n0r; v0i=n0i; v1r=n1r; v1i=n1i;
            }
            if (yb) {
                float n0r = cy*v0r - sy*v1r, n0i = cy*v0i - sy*v1i;
                float n1r = sy*v0r + cy*v1r, n1i = sy*v0i + cy*v1i;
                v0r=n0r; v0i=n0i; v1r=n1r; v1i=n1i;
            }
            if (xb) {
                float n0r = cz*v0r + sz*v0i, n0i = cz*v0i - sz*v0r;
                float n1r = cz*v1r - sz*v1i, n1i = cz*v1i + sz*v1r;
                v0r=n0r; v0i=n0i; v1r=n1r; v1i=n1i;
            }
        }
        float4 g;
        g.x = v0r*v0r + v0i*v0i;
        g.y = v1r*v1r + v1i*v1i;
        g.z = v0r*v1r + v0i*v1i;   // Re(p0 p1*)
        g.w = v0i*v1r - v0r*v1i;   // Im(p0 p1*)
        sPhi[tid] = g;
    } else if (tid == 64) {
        // U = CNOT(7,3) CNOT(3,7) (Ra (x) Rb), basis idx = 2*w3 + w7; row perm {0,2,3,1}
        float Ra[2][2][2], Rb[2][2][2];
        rot2(update[0], update[1], update[2], Ra);
        rot2(update[3], update[4], update[5], Rb);
        const int src[4] = {0, 2, 3, 1};
        #pragma unroll
        for (int k = 0; k < 4; ++k) {
            int r = src[k], r3 = r >> 1, r7 = r & 1;
            #pragma unroll
            for (int c = 0; c < 4; ++c) {
                int c3 = c >> 1, c7 = c & 1;
                float ar = Ra[r3][c3][0], ai = Ra[r3][c3][1];
                float br = Rb[r7][c7][0], bi = Rb[r7][c7][1];
                sUm[(k*4+c)*2 + 0] = ar*br - ai*bi;
                sUm[(k*4+c)*2 + 1] = ar*bi + ai*br;
            }
        }
    }
    __syncthreads();

    const int half  = tid & 1;
    const int hbase = half << 6;           // this half's h-range start
    int n0 = blockIdx.x * 128 + (tid >> 1);
    bool valid = n0 < N;
    int nn = valid ? n0 : 0;

    const int4 sn = ((const int4*)sub_nodes)[nn];
    const int se0 = sub_edges[3*(size_t)nn+0];
    const int se1 = sub_edges[3*(size_t)nn+1];
    const int se2 = sub_edges[3*(size_t)nn+2];

    // ---- gather all inputs up front (hide latency under edge loop) ----
    const float4* ep0 = (const float4*)(edge_attr + (size_t)se0*8);
    const float4* ep1 = (const float4*)(edge_attr + (size_t)se1*8);
    const float4* ep2 = (const float4*)(edge_attr + (size_t)se2*8);
    float4 e0a=ep0[0], e0b=ep0[1], e1a=ep1[0], e1b=ep1[1], e2a=ep2[0], e2b=ep2[1];
    const float4* xp = (const float4*)(node_feat + (size_t)nn*16);
    float4 x0=xp[0], x1=xp[1], x2=xp[2], x3=xp[3];
    const float4* yp = (const float4*)(node_feat + (size_t)sn.y*16);
    float4 y0=yp[0], y1=yp[1], y2=yp[2], y3=yp[3];
    const float4* zp = (const float4*)(node_feat + (size_t)sn.z*16);
    float4 z0=zp[0], z1=zp[1], z2=zp[2], z3=zp[3];
    const float4* wp = (const float4*)(node_feat + (size_t)sn.w*16);
    float4 w0=wp[0], w1=wp[1], w2=wp[2], w3=wp[3];

    // ---- edge MLP x3 (a-col only), h split across the pair ----
    float aE0=0.f, aE1=0.f, aE2=0.f;
    #pragma unroll 4
    for (int j = 0; j < 64; ++j) {
        const float4* r = (const float4*)&sE[(j+hbase)*12];
        float4 f0=r[0], f1=r[1], f2=r[2];
        float t0=f2.x, t1=f2.x, t2=f2.x;
        t0=fmaf(e0a.x,f0.x,t0); t1=fmaf(e1a.x,f0.x,t1); t2=fmaf(e2a.x,f0.x,t2);
        t0=fmaf(e0a.y,f0.y,t0); t1=fmaf(e1a.y,f0.y,t1); t2=fmaf(e2a.y,f0.y,t2);
        t0=fmaf(e0a.z,f0.z,t0); t1=fmaf(e1a.z,f0.z,t1); t2=fmaf(e2a.z,f0.z,t2);
        t0=fmaf(e0a.w,f0.w,t0); t1=fmaf(e1a.w,f0.w,t1); t2=fmaf(e2a.w,f0.w,t2);
        t0=fmaf(e0b.x,f1.x,t0); t1=fmaf(e1b.x,f1.x,t1); t2=fmaf(e2b.x,f1.x,t2);
        t0=fmaf(e0b.y,f1.y,t0); t1=fmaf(e1b.y,f1.y,t1); t2=fmaf(e2b.y,f1.y,t2);
        t0=fmaf(e0b.z,f1.z,t0); t1=fmaf(e1b.z,f1.z,t1); t2=fmaf(e2b.z,f1.z,t2);
        t0=fmaf(e0b.w,f1.w,t0); t1=fmaf(e1b.w,f1.w,t1); t2=fmaf(e2b.w,f1.w,t2);
        float l0 = t0>0.f ? t0 : 0.01f*t0;
        float l1 = t1>0.f ? t1 : 0.01f*t1;
        float l2 = t2>0.f ? t2 : 0.01f*t2;
        aE0 = fmaf(l0, f2.y, aE0);
        aE1 = fmaf(l1, f2.y, aE1);
        aE2 = fmaf(l2, f2.y, aE2);
    }
    aE0 += __shfl_xor(aE0,1); aE1 += __shfl_xor(aE1,1); aE2 += __shfl_xor(aE2,1);

    // ---- node MLP: own (a,b) + 3 neighbors (a only), h split ----
    float aN0=0.f, aN1=0.f, aY=0.f, aZ=0.f, aWn=0.f;
    #pragma unroll 2
    for (int j = 0; j < 64; ++j) {
        const float4* r = (const float4*)&sN[(j+hbase)*20];
        float4 f0=r[0], f1=r[1], f2=r[2], f3=r[3], f4=r[4];
        float tx=f4.x, ty=f4.x, tz=f4.x, tw=f4.x;
        tx=fmaf(x0.x,f0.x,tx); ty=fmaf(y0.x,f0.x,ty); tz=fmaf(z0.x,f0.x,tz); tw=fmaf(w0.x,f0.x,tw);
        tx=fmaf(x0.y,f0.y,tx); ty=fmaf(y0.y,f0.y,ty); tz=fmaf(z0.y,f0.y,tz); tw=fmaf(w0.y,f0.y,tw);
        tx=fmaf(x0.z,f0.z,tx); ty=fmaf(y0.z,f0.z,ty); tz=fmaf(z0.z,f0.z,tz); tw=fmaf(w0.z,f0.z,tw);
        tx=fmaf(x0.w,f0.w,tx); ty=fmaf(y0.w,f0.w,ty); tz=fmaf(z0.w,f0.w,tz); tw=fmaf(w0.w,f0.w,tw);
        tx=fmaf(x1.x,f1.x,tx); ty=fmaf(y1.x,f1.x,ty); tz=fmaf(z1.x,f1.x,tz); tw=fmaf(w1.x,f1.x,tw);
        tx=fmaf(x1.y,f1.y,tx); ty=fmaf(y1.y,f1.y,ty); tz=fmaf(z1.y,f1.y,tz); tw=fmaf(w1.y,f1.y,tw);
        tx=fmaf(x1.z,f1.z,tx); ty=fmaf(y1.z,f1.z,ty); tz=fmaf(z1.z,f1.z,tz); tw=fmaf(w1.z,f1.z,tw);
        tx=fmaf(x1.w,f1.w,tx); ty=fmaf(y1.w,f1.w,ty); tz=fmaf(z1.w,f1.w,tz); tw=fmaf(w1.w,f1.w,tw);
        tx=fmaf(x2.x,f2.x,tx); ty=fmaf(y2.x,f2.x,ty); tz=fmaf(z2.x,f2.x,tz); tw=fmaf(w2.x,f2.x,tw);
        tx=fmaf(x2.y,f2.y,tx); ty=fmaf(y2.y,f2.y,ty); tz=fmaf(z2.y,f2.y,tz); tw=fmaf(w2.y,f2.y,tw);
        tx=fmaf(x2.z,f2.z,tx); ty=fmaf(y2.z,f2.z,ty); tz=fmaf(z2.z,f2.z,tz); tw=fmaf(w2.z,f2.z,tw);
        tx=fmaf(x2.w,f2.w,tx); ty=fmaf(y2.w,f2.w,ty); tz=fmaf(z2.w,f2.w,tz); tw=fmaf(w2.w,f2.w,tw);
        tx=fmaf(x3.x,f3.x,tx); ty=fmaf(y3.x,f3.x,ty); tz=fmaf(z3.x,f3.x,tz); tw=fmaf(w3.x,f3.x,tw);
        tx=fmaf(x3.y,f3.y,tx); ty=fmaf(y3.y,f3.y,ty); tz=fmaf(z3.y,f3.y,tz); tw=fmaf(w3.y,f3.y,tw);
        tx=fmaf(x3.z,f3.z,tx); ty=fmaf(y3.z,f3.z,ty); tz=fmaf(z3.z,f3.z,tz); tw=fmaf(w3.z,f3.z,tw);
        tx=fmaf(x3.w,f3.w,tx); ty=fmaf(y3.w,f3.w,ty); tz=fmaf(z3.w,f3.w,tz); tw=fmaf(w3.w,f3.w,tw);
        float lx = tx>0.f ? tx : 0.01f*tx;
        float ly = ty>0.f ? ty : 0.01f*ty;
        float lz = tz>0.f ? tz : 0.01f*tz;
        float lw = tw>0.f ? tw : 0.01f*tw;
        aN0 = fmaf(lx, f4.y, aN0); aN1 = fmaf(lx, f4.z, aN1);
        aY  = fmaf(ly, f4.y, aY);
        aZ  = fmaf(lz, f4.y, aZ);
        aWn = fmaf(lw, f4.y, aWn);
    }
    aN0 += __shfl_xor(aN0,1); aN1 += __shfl_xor(aN1,1);
    aY  += __shfl_xor(aY,1);  aZ  += __shfl_xor(aZ,1); aWn += __shfl_xor(aWn,1);

    float eb2_0 = eb2[0], nb2_0 = nb2[0], nb2_1 = nb2[1];
    float ae0 = tanhf(aE0 + eb2_0) * PI_F;
    float ae1 = tanhf(aE1 + eb2_0) * PI_F;
    float ae2 = tanhf(aE2 + eb2_0) * PI_F;
    float a3  = tanhf(aN0 + nb2_0) * PI_F;   // own a-angle (wire 3)
    float b3  = tanhf(aN1 + nb2_1) * PI_F;   // own b-angle
    float ay  = tanhf(aY  + nb2_0) * PI_F;
    float az  = tanhf(aZ  + nb2_0) * PI_F;
    float aw  = tanhf(aWn + nb2_0) * PI_F;

    // ---- circuit marginal: control weights cos^2(a/2) = (1+cos a)/2 ----
    float c0 = cosf(ae0), c1 = cosf(ae1), c2 = cosf(ae2);
    float d0 = cosf(ay),  d1 = cosf(az),  d2 = cosf(aw);
    float pe00=0.5f*(1.f+c0), pe01=0.5f*(1.f-c0);
    float pe10=0.5f*(1.f+c1), pe11=0.5f*(1.f-c1);
    float pe20=0.5f*(1.f+c2), pe21=0.5f*(1.f-c2);
    float pn00=0.5f*(1.f+d0), pn01=0.5f*(1.f-d0);
    float pn10=0.5f*(1.f+d1), pn11=0.5f*(1.f-d1);
    float pn20=0.5f*(1.f+d2), pn21=0.5f*(1.f-d2);
    float E[8], Nw[8];
    #pragma unroll
    for (int m = 0; m < 8; ++m) {
        E[m]  = ((m&1)?pe01:pe00) * ((m&2)?pe11:pe10) * ((m&4)?pe21:pe20);
        Nw[m] = ((m&1)?pn01:pn00) * ((m&2)?pn11:pn10) * ((m&4)?pn21:pn20);
    }
    float S0=0.f, S1=0.f, Sr=0.f, Si=0.f;
    #pragma unroll
    for (int q = 0; q < 4; ++q) {
        float Nq = half ? Nw[4+q] : Nw[q];
        #pragma unroll
        for (int p = 0; p < 8; ++p) {
            float W = E[p] * Nq;
            float4 g = sPhi[(half<<5) + q*8 + p];
            S0 = fmaf(W, g.x, S0); S1 = fmaf(W, g.y, S1);
            Sr = fmaf(W, g.z, Sr); Si = fmaf(W, g.w, Si);
        }
    }
    S0 += __shfl_xor(S0,1); S1 += __shfl_xor(S1,1);
    Sr += __shfl_xor(Sr,1); Si += __shfl_xor(Si,1);

    // center qubit + T = U (q3 (x) I) ; P[k]
    float ca = cosf(0.5f*a3), sa = sinf(0.5f*a3);
    float cb = cosf(0.5f*b3), sb = sinf(0.5f*b3);
    float q0r = ca*cb, q0i = -ca*sb, q1r = sa*cb, q1i = sa*sb;
    float P[4];
    #pragma unroll
    for (int k = 0; k < 4; ++k) {
        float u0r = sUm[(k*4+0)*2], u0i = sUm[(k*4+0)*2+1];
        float u1r = sUm[(k*4+2)*2], u1i = sUm[(k*4+2)*2+1];
        float T0r = u0r*q0r - u0i*q0i + u1r*q1r - u1i*q1i;
        float T0i = u0r*q0i + u0i*q0r + u1r*q1i + u1i*q1r;
        float w0r = sUm[(k*4+1)*2], w0i = sUm[(k*4+1)*2+1];
        float w1r = sUm[(k*4+3)*2], w1i = sUm[(k*4+3)*2+1];
        float T1r = w0r*q0r - w0i*q0i + w1r*q1r - w1i*q1i;
        float T1i = w0r*q0i + w0i*q0r + w1r*q1i + w1i*q1r;
        float Ar = T0r*T1r + T0i*T1i, Ai = T0i*T1r - T0r*T1i;
        P[k] = (T0r*T0r + T0i*T0i)*S0 + (T1r*T1r + T1i*T1i)*S1 + 2.f*(Ar*Sr - Ai*Si);
    }

    // ---- upd MLP (6->128->2), h split ----
    float u0 = 0.f, u1 = 0.f;
    #pragma unroll 4
    for (int j = 0; j < 64; ++j) {
        const float4* r = (const float4*)&sU[(j+hbase)*12];
        float4 f0=r[0], f1=r[1], f2=r[2];
        float t = f1.z;
        t = fmaf(a3,   f0.x, t); t = fmaf(b3,   f0.y, t);
        t = fmaf(P[0], f0.z, t); t = fmaf(P[1], f0.w, t);
        t = fmaf(P[2], f1.x, t); t = fmaf(P[3], f1.y, t);
        float lt = t > 0.f ? t : 0.01f*t;
        u0 = fmaf(lt, f1.w, u0);
        u1 = fmaf(lt, f2.x, u1);
    }
    u0 += __shfl_xor(u0,1); u1 += __shfl_xor(u1,1);

    // x = 1.5*nf + 0.5*upd (centers == arange(N)); LayerNorm over 2 features
    float x0v = 1.5f*a3 + 0.5f*(tanhf(u0 + ub2[0]) * PI_F);
    float x1v = 1.5f*b3 + 0.5f*(tanhf(u1 + ub2[1]) * PI_F);
    float mu  = 0.5f*(x0v + x1v);
    float dd  = x0v - mu;
    float inv = 1.0f / sqrtf(dd*dd + 1e-5f);
    float wv  = valid ? 1.f : 0.f;
    float xn0 = ( dd*inv*lng[0] + lnb[0]) * wv;
    float xn1 = (-dd*inv*lng[1] + lnb[1]) * wv;
    int bs = batch[nn];

    // ---- per-block segment partials (each node counted twice -> x0.5) ----
    bool uni = __all(bs == __shfl(bs, 0));
    if (uni) {
        float r0 = xn0, r1 = xn1, rc = wv;
        #pragma unroll
        for (int off = 32; off >= 1; off >>= 1) {
            r0 += __shfl_xor(r0, off); r1 += __shfl_xor(r1, off); rc += __shfl_xor(rc, off);
        }
        if ((tid & 63) == 0) {
            atomicAdd(&sseg[bs*3+0], 0.5f*r0);
            atomicAdd(&sseg[bs*3+1], 0.5f*r1);
            atomicAdd(&sseg[bs*3+2], 0.5f*rc);
        }
    } else if (valid && half == 0) {
        atomicAdd(&sseg[bs*3+0], xn0);
        atomicAdd(&sseg[bs*3+1], xn1);
        atomicAdd(&sseg[bs*3+2], 1.f);
    }
    __syncthreads();
    for (int idx = tid; idx < 96; idx += 256)
        part[(size_t)idx * nb + blockIdx.x] = sseg[idx];   // transposed for coalesced k_head reads

// (plain store, no init needed)
}

// ---- k_head: parallel reduce of per-block partials + head MLP (2->2 leaky 2->2) ----
__global__ __launch_bounds__(256) void k_head(
    const float* __restrict__ part, int nb,
    const float* __restrict__ hW1, const float* __restrict__ hb1,
    const float* __restrict__ hW2, const float* __restrict__ hb2,
    float* __restrict__ out)
{
    __shared__ float tot[96];
    const int tid  = threadIdx.x;
    const int wave = tid >> 6;      // 4 waves, 24 rows each
    const int lane = tid & 63;

    float acc[24];
    #pragma unroll
    for (int rr = 0; rr < 24; ++rr) acc[rr] = 0.f;
    for (int c = lane; c < nb; c += 64) {
        #pragma unroll
        for (int rr = 0; rr < 24; ++rr)
            acc[rr] += part[(size_t)(wave*24 + rr) * nb + c];   // 24 coalesced loads in flight
    }
    #pragma unroll
    for (int rr = 0; rr < 24; ++rr) {
        float s = acc[rr];
        #pragma unroll
        for (int off = 32; off >= 1; off >>= 1) s += __shfl_xor(s, off);
        if (lane == 0) tot[wave*24 + rr] = s;
    }
    __syncthreads();
    if (tid < 32) {
        float c  = tot[tid*3+2];
        float iv = c > 0.f ? 1.f/c : 0.f;
        float g0 = tot[tid*3+0]*iv, g1 = tot[tid*3+1]*iv;
        float a = hb1[0] + g0*hW1[0] + g1*hW1[2];
        float b = hb1[1] + g0*hW1[1] + g1*hW1[3];
        float h0 = a > 0.f ? a : 0.01f*a;
        float h1 = b > 0.f ? b : 0.01f*b;
        out[tid*2+0] = hb2[0] + h0*hW2[0] + h1*hW2[2];
        out[tid*2+1] = hb2[1] + h0*hW2[1] + h1*hW2[3];
    }
}

extern "C" void kernel_launch(void* const* d_in, const int* in_sizes, int n_in,
                              void* d_out, int out_size, void* d_ws, size_t ws_size,
                              hipStream_t stream)
{
    const float* node_feat = (const float*)d_in[0];
    const float* edge_attr = (const float*)d_in[1];
    const float* node_W1 = (const float*)d_in[2];
    const float* node_b1 = (const float*)d_in[3];
    const float* node_W2 = (const float*)d_in[4];
    const float* node_b2 = (const float*)d_in[5];
    const float* edge_W1 = (const float*)d_in[6];
    const float* edge_b1 = (const float*)d_in[7];
    const float* edge_W2 = (const float*)d_in[8];
    const float* edge_b2 = (const float*)d_in[9];
    const float* inits   = (const float*)d_in[10];
    const float* update  = (const float*)d_in[11];
    const float* upd_W1  = (const float*)d_in[12];
    const float* upd_b1  = (const float*)d_in[13];
    const float* upd_W2  = (const float*)d_in[14];
    const float* upd_b2  = (const float*)d_in[15];
    const float* ln_g    = (const float*)d_in[16];
    const float* ln_b    = (const float*)d_in[17];
    const float* head_W1 = (const float*)d_in[18];
    const float* head_b1 = (const float*)d_in[19];
    const float* head_W2 = (const float*)d_in[20];
    const float* head_b2 = (const float*)d_in[21];
    const int* sub_nodes = (const int*)d_in[22];
    const int* sub_edges = (const int*)d_in[23];
    const int* batch     = (const int*)d_in[24];

    int N  = in_sizes[24];           // 32768
    int nb = (N + 127) / 128;        // 256 blocks

    float* part = (float*)d_ws;
    if (ws_size < (size_t)nb * 96 * sizeof(float)) return;

    k_all<<<nb, 256, 0, stream>>>(node_feat, edge_attr,
        node_W1, node_b1, node_W2, node_b2,
        edge_W1, edge_b1, edge_W2, edge_b2,
        upd_W1, upd_b1, upd_W2, upd_b2,
        inits, update, ln_g, ln_b,
        sub_nodes, sub_edges, batch,
        part, N, nb);
    k_head<<<1, 256, 0, stream>>>(part, nb,
        head_W1, head_b1, head_W2, head_b2, (float*)d_out);
}

// Round 11
// 44.406 us; speedup vs baseline: 1.9981x; 1.1835x over previous
//
#include <hip/hip_runtime.h>
#include <math.h>

static constexpr float PI_F = 3.14159265358979323846f;

// dims: N=32768 nodes, NE=3N edges, H=128, PQC=2
// ws layout (floats):
//   [0..96)    seg: 32 x {sum0, sum1, count}
//   [96]       int counter (last-block election)
//   [128..384) phi table: 64 x {|p0|^2, |p1|^2, Re(p0 p1*), Im(p0 p1*)}
//   [384..416) U: 4x4 complex row-major [k][c][re,im]
//   [512..512+2N)      nf  (float2 per node: a,b)
//   [512+2N..512+2N+NE) ef1 (edge a only; edge b provably drops out)

__device__ inline void rot2(float p, float t, float o, float R[2][2][2]) {
    // Rot(p,t,o) = Rz(o) Ry(t) Rz(p)
    float ct = cosf(0.5f*t), st = sinf(0.5f*t);
    float apo = 0.5f*(p+o), amo = 0.5f*(p-o);
    R[0][0][0] =  ct*cosf(apo); R[0][0][1] = -ct*sinf(apo);
    R[0][1][0] = -st*cosf(amo); R[0][1][1] = -st*sinf(amo);
    R[1][0][0] =  st*cosf(amo); R[1][0][1] = -st*sinf(amo);
    R[1][1][0] =  ct*cosf(apo); R[1][1][1] =  ct*sinf(apo);
}

// --- kernel A: setup (block 0) + edge MLP (blocks [0,nbE)) + node MLP (rest) ---
// Weights read directly from global with wave-uniform indices -> s_load (no LDS).
__global__ __launch_bounds__(256) void k_mlp(
    const float* __restrict__ node_feat, const float* __restrict__ edge_attr,
    const float* __restrict__ nW1, const float* __restrict__ nb1,
    const float* __restrict__ nW2, const float* __restrict__ nb2,
    const float* __restrict__ eW1, const float* __restrict__ eb1,
    const float* __restrict__ eW2, const float* __restrict__ eb2,
    const float* __restrict__ inits, const float* __restrict__ update,
    float* __restrict__ ws, int N, int NE, int nbE)
{
    const int tid = threadIdx.x;
    const int blk = blockIdx.x;

    if (blk == 0) {
        // zero segment accumulators + counter (harness doesn't re-poison between replays)
        if (tid < 96) ws[tid] = 0.f;
        if (tid == 96) ((int*)ws)[96] = 0;
        if (tid < 64) {
            // phi table: wire-7 state for control pattern tid
            // bits 0..2 = wires 0,1,2 (CRY ctrl), bits 3..5 = wires 4,5,6 (CRX/CRZ ctrl)
            float cx = cosf(0.5f*inits[0]), sx = sinf(0.5f*inits[0]);
            float cy = cosf(0.5f*inits[1]), sy = sinf(0.5f*inits[1]);
            float cz = cosf(0.5f*inits[2]), sz = sinf(0.5f*inits[2]);
            float v0r = 1.f, v0i = 0.f, v1r = 0.f, v1i = 0.f;
            #pragma unroll
            for (int i = 0; i < 3; ++i) {
                int xb = (tid >> (3+i)) & 1;
                int yb = (tid >> i) & 1;
                if (xb) { // Rx
                    float n0r = cx*v0r + sx*v1i, n0i = cx*v0i - sx*v1r;
                    float n1r = sx*v0i + cx*v1r, n1i = -sx*v0r + cx*v1i;
                    v0r=n0r; v0i=n0i; v1r=n1r; v1i=n1i;
                }
                if (yb) { // Ry
                    float n0r = cy*v0r - sy*v1r, n0i = cy*v0i - sy*v1i;
                    float n1r = sy*v0r + cy*v1r, n1i = sy*v0i + cy*v1i;
                    v0r=n0r; v0i=n0i; v1r=n1r; v1i=n1i;
                }
                if (xb) { // Rz
                    float n0r = cz*v0r + sz*v0i, n0i = cz*v0i - sz*v0r;
                    float n1r = cz*v1r - sz*v1i, n1i = cz*v1i + sz*v1r;
                    v0r=n0r; v0i=n0i; v1r=n1r; v1i=n1i;
                }
            }
            ws[128 + tid*4 + 0] = v0r*v0r + v0i*v0i;
            ws[128 + tid*4 + 1] = v1r*v1r + v1i*v1i;
            ws[128 + tid*4 + 2] = v0r*v1r + v0i*v1i;   // Re(p0 p1*)
            ws[128 + tid*4 + 3] = v0i*v1r - v0r*v1i;   // Im(p0 p1*)
        } else if (tid == 64) {
            // U = CNOT(7,3) CNOT(3,7) (Ra (x) Rb), basis idx = 2*w3 + w7; row perm {0,2,3,1}
            float Ra[2][2][2], Rb[2][2][2];
            rot2(update[0], update[1], update[2], Ra);
            rot2(update[3], update[4], update[5], Rb);
            const int src[4] = {0, 2, 3, 1};
            #pragma unroll
            for (int k = 0; k < 4; ++k) {
                int r = src[k], r3 = r >> 1, r7 = r & 1;
                #pragma unroll
                for (int c = 0; c < 4; ++c) {
                    int c3 = c >> 1, c7 = c & 1;
                    float ar = Ra[r3][c3][0], ai = Ra[r3][c3][1];
                    float br = Rb[r7][c7][0], bi = Rb[r7][c7][1];
                    ws[384 + (k*4+c)*2 + 0] = ar*br - ai*bi;
                    ws[384 + (k*4+c)*2 + 1] = ar*bi + ai*br;
                }
            }
        }
    }

    if (blk < nbE) {
        // ---- edge MLP: (8->128->1), only output col 0 (edge b drops out of circuit) ----
        int e = blk * 256 + tid;
        if (e >= NE) return;
        const float4* xp = (const float4*)(edge_attr + (size_t)e * 8);
        float4 v0 = xp[0], v1 = xp[1];
        float x[8] = {v0.x,v0.y,v0.z,v0.w, v1.x,v1.y,v1.z,v1.w};
        float t[128];
        #pragma unroll
        for (int h = 0; h < 128; ++h) t[h] = eb1[h];
        #pragma unroll
        for (int i = 0; i < 8; ++i) {
            const float* row = eW1 + i*128;
            float xi = x[i];
            #pragma unroll
            for (int h = 0; h < 128; ++h) t[h] = fmaf(xi, row[h], t[h]);
        }
        float acc = 0.f;
        #pragma unroll
        for (int h = 0; h < 128; ++h) {
            float lt = t[h] > 0.f ? t[h] : 0.01f * t[h];
            acc = fmaf(lt, eW2[2*h], acc);
        }
        ws[512 + 2*(size_t)N + e] = tanhf(acc + eb2[0]) * PI_F;
    } else {
        // ---- node MLP: (16->128->2) ----
        int n = (blk - nbE) * 256 + tid;
        if (n >= N) return;
        const float4* xp = (const float4*)(node_feat + (size_t)n * 16);
        float4 v0 = xp[0], v1 = xp[1], v2 = xp[2], v3 = xp[3];
        float x[16] = {v0.x,v0.y,v0.z,v0.w, v1.x,v1.y,v1.z,v1.w,
                       v2.x,v2.y,v2.z,v2.w, v3.x,v3.y,v3.z,v3.w};
        float t[128];
        #pragma unroll
        for (int h = 0; h < 128; ++h) t[h] = nb1[h];
        #pragma unroll
        for (int i = 0; i < 16; ++i) {
            const float* row = nW1 + i*128;
            float xi = x[i];
            #pragma unroll
            for (int h = 0; h < 128; ++h) t[h] = fmaf(xi, row[h], t[h]);
        }
        float a0 = 0.f, a1 = 0.f;
        #pragma unroll
        for (int h = 0; h < 128; ++h) {
            float lt = t[h] > 0.f ? t[h] : 0.01f * t[h];
            a0 = fmaf(lt, nW2[2*h],   a0);
            a1 = fmaf(lt, nW2[2*h+1], a1);
        }
        float2 o;
        o.x = tanhf(a0 + nb2[0]) * PI_F;
        o.y = tanhf(a1 + nb2[1]) * PI_F;
        ((float2*)(ws + 512))[n] = o;
    }
}

// --- kernel B: analytic circuit + upd MLP + LN + segment reduce + (last block) head ---
__global__ __launch_bounds__(256) void k_circ(
    float* __restrict__ ws,
    const float* __restrict__ uW1, const float* __restrict__ ub1,
    const float* __restrict__ uW2, const float* __restrict__ ub2,
    const float* __restrict__ lng, const float* __restrict__ lnb,
    const int* __restrict__ sub_nodes, const int* __restrict__ sub_edges,
    const int* __restrict__ batch,
    const float* __restrict__ hW1, const float* __restrict__ hb1,
    const float* __restrict__ hW2, const float* __restrict__ hb2,
    float* __restrict__ out, int N)
{
    const int tid = threadIdx.x;
    const float2* nf  = (const float2*)(ws + 512);
    const float* ef1  = ws + 512 + 2*(size_t)N;
    const float4* phi4 = (const float4*)(ws + 128);
    const float* U    = ws + 384;

    int n0 = blockIdx.x * 256 + tid;
    bool valid = n0 < N;
    int n = valid ? n0 : N - 1;

    const int4 sn = ((const int4*)sub_nodes)[n];
    int se0 = sub_edges[3*(size_t)n+0], se1 = sub_edges[3*(size_t)n+1], se2 = sub_edges[3*(size_t)n+2];

    // control-wire probability weights (only a-angle matters; cos^2(a/2)=(1+cos a)/2)
    float pe[3][2], pn[3][2];
    {
        float c0 = cosf(ef1[se0]), c1 = cosf(ef1[se1]), c2 = cosf(ef1[se2]);
        pe[0][0]=0.5f*(1.f+c0); pe[0][1]=0.5f*(1.f-c0);
        pe[1][0]=0.5f*(1.f+c1); pe[1][1]=0.5f*(1.f-c1);
        pe[2][0]=0.5f*(1.f+c2); pe[2][1]=0.5f*(1.f-c2);
        float d0 = cosf(nf[sn.y].x), d1 = cosf(nf[sn.z].x), d2 = cosf(nf[sn.w].x);
        pn[0][0]=0.5f*(1.f+d0); pn[0][1]=0.5f*(1.f-d0);
        pn[1][0]=0.5f*(1.f+d1); pn[1][1]=0.5f*(1.f-d1);
        pn[2][0]=0.5f*(1.f+d2); pn[2][1]=0.5f*(1.f-d2);
    }
    float E[8], Nw[8];
    #pragma unroll
    for (int m = 0; m < 8; ++m) {
        E[m]  = pe[0][m&1] * pe[1][(m>>1)&1] * pe[2][(m>>2)&1];
        Nw[m] = pn[0][m&1] * pn[1][(m>>1)&1] * pn[2][(m>>2)&1];
    }
    float S0 = 0.f, S1 = 0.f, Sr = 0.f, Si = 0.f;
    #pragma unroll
    for (int m = 0; m < 64; ++m) {
        float W = E[m & 7] * Nw[m >> 3];
        float4 g = phi4[m];
        S0 = fmaf(W, g.x, S0); S1 = fmaf(W, g.y, S1);
        Sr = fmaf(W, g.z, Sr); Si = fmaf(W, g.w, Si);
    }
    // center qubit + T = U (q3 (x) I)
    float2 nfc = nf[sn.x];
    float ca = cosf(0.5f*nfc.x), sa = sinf(0.5f*nfc.x);
    float cb = cosf(0.5f*nfc.y), sb = sinf(0.5f*nfc.y);
    float q0r = ca*cb, q0i = -ca*sb, q1r = sa*cb, q1i = sa*sb;
    float P[4];
    #pragma unroll
    for (int k = 0; k < 4; ++k) {
        float T0r, T0i, T1r, T1i;
        {
            float u0r = U[(k*4+0)*2], u0i = U[(k*4+0)*2+1];
            float u1r = U[(k*4+2)*2], u1i = U[(k*4+2)*2+1];
            T0r = u0r*q0r - u0i*q0i + u1r*q1r - u1i*q1i;
            T0i = u0r*q0i + u0i*q0r + u1r*q1i + u1i*q1r;
        }
        {
            float u0r = U[(k*4+1)*2], u0i = U[(k*4+1)*2+1];
            float u1r = U[(k*4+3)*2], u1i = U[(k*4+3)*2+1];
            T1r = u0r*q0r - u0i*q0i + u1r*q1r - u1i*q1i;
            T1i = u0r*q0i + u0i*q0r + u1r*q1i + u1i*q1r;
        }
        float Ar = T0r*T1r + T0i*T1i, Ai = T0i*T1r - T0r*T1i;
        P[k] = (T0r*T0r + T0i*T0i)*S0 + (T1r*T1r + T1i*T1i)*S1 + 2.f*(Ar*Sr - Ai*Si);
    }
    // upd MLP (6->128->2), weights via uniform s_load
    float in6[6] = {nfc.x, nfc.y, P[0], P[1], P[2], P[3]};
    float t[128];
    #pragma unroll
    for (int h = 0; h < 128; ++h) t[h] = ub1[h];
    #pragma unroll
    for (int i = 0; i < 6; ++i) {
        const float* row = uW1 + i*128;
        float xi = in6[i];
        #pragma unroll
        for (int h = 0; h < 128; ++h) t[h] = fmaf(xi, row[h], t[h]);
    }
    float u0 = 0.f, u1 = 0.f;
    #pragma unroll
    for (int h = 0; h < 128; ++h) {
        float lt = t[h] > 0.f ? t[h] : 0.01f * t[h];
        u0 = fmaf(lt, uW2[2*h],   u0);
        u1 = fmaf(lt, uW2[2*h+1], u1);
    }
    // x = 1.5*nf + 0.5*upd (centers == arange(N)); LayerNorm over 2 features
    float x0 = 1.5f*nfc.x + 0.5f*(tanhf(u0 + ub2[0]) * PI_F);
    float x1 = 1.5f*nfc.y + 0.5f*(tanhf(u1 + ub2[1]) * PI_F);
    float mu = 0.5f*(x0 + x1);
    float d  = x0 - mu;
    float inv = 1.0f / sqrtf(d*d + 1e-5f);
    float wv  = valid ? 1.f : 0.f;
    float xn0 = ( d*inv*lng[0] + lnb[0]) * wv;
    float xn1 = (-d*inv*lng[1] + lnb[1]) * wv;
    int bs = batch[n];

    // segment accumulate: wave-uniform fast path (batch is sorted), per-lane fallback
    bool uni = __all(bs == __shfl(bs, 0));
    if (uni) {
        float r0 = xn0, r1 = xn1, rc = wv;
        #pragma unroll
        for (int off = 32; off >= 1; off >>= 1) {
            r0 += __shfl_xor(r0, off); r1 += __shfl_xor(r1, off); rc += __shfl_xor(rc, off);
        }
        if ((tid & 63) == 0) {
            atomicAdd(&ws[bs*3+0], r0);
            atomicAdd(&ws[bs*3+1], r1);
            atomicAdd(&ws[bs*3+2], rc);
        }
    } else if (valid) {
        atomicAdd(&ws[bs*3+0], xn0);
        atomicAdd(&ws[bs*3+1], xn1);
        atomicAdd(&ws[bs*3+2], 1.f);
    }

    // last-block election -> head MLP (2->2 leaky 2->2) on segment means
    __shared__ int sLast;
    __threadfence();
    __syncthreads();
    if (tid == 0) {
        int old = atomicAdd((int*)ws + 96, 1);
        sLast = (old == (int)gridDim.x - 1) ? 1 : 0;
    }
    __syncthreads();
    if (sLast && tid < 32) {
        // device-scope atomic reads for cross-XCD coherence
        float cnt = atomicAdd(&ws[tid*3+2], 0.f);
        float iv  = cnt > 0.f ? 1.f/cnt : 0.f;
        float g0  = atomicAdd(&ws[tid*3+0], 0.f) * iv;
        float g1  = atomicAdd(&ws[tid*3+1], 0.f) * iv;
        float h0, h1;
        {
            float a = hb1[0] + g0*hW1[0] + g1*hW1[2];
            float b = hb1[1] + g0*hW1[1] + g1*hW1[3];
            h0 = a > 0.f ? a : 0.01f*a;
            h1 = b > 0.f ? b : 0.01f*b;
        }
        out[tid*2+0] = hb2[0] + h0*hW2[0] + h1*hW2[2];
        out[tid*2+1] = hb2[1] + h0*hW2[1] + h1*hW2[3];
    }
}

extern "C" void kernel_launch(void* const* d_in, const int* in_sizes, int n_in,
                              void* d_out, int out_size, void* d_ws, size_t ws_size,
                              hipStream_t stream)
{
    const float* node_feat = (const float*)d_in[0];
    const float* edge_attr = (const float*)d_in[1];
    const float* node_W1 = (const float*)d_in[2];
    const float* node_b1 = (const float*)d_in[3];
    const float* node_W2 = (const float*)d_in[4];
    const float* node_b2 = (const float*)d_in[5];
    const float* edge_W1 = (const float*)d_in[6];
    const float* edge_b1 = (const float*)d_in[7];
    const float* edge_W2 = (const float*)d_in[8];
    const float* edge_b2 = (const float*)d_in[9];
    const float* inits   = (const float*)d_in[10];
    const float* update  = (const float*)d_in[11];
    const float* upd_W1  = (const float*)d_in[12];
    const float* upd_b1  = (const float*)d_in[13];
    const float* upd_W2  = (const float*)d_in[14];
    const float* upd_b2  = (const float*)d_in[15];
    const float* ln_g    = (const float*)d_in[16];
    const float* ln_b    = (const float*)d_in[17];
    const float* head_W1 = (const float*)d_in[18];
    const float* head_b1 = (const float*)d_in[19];
    const float* head_W2 = (const float*)d_in[20];
    const float* head_b2 = (const float*)d_in[21];
    const int* sub_nodes = (const int*)d_in[22];
    const int* sub_edges = (const int*)d_in[23];
    const int* batch     = (const int*)d_in[24];

    int N  = in_sizes[24];      // 32768
    int NE = in_sizes[1] / 8;   // 98304

    float* w = (float*)d_ws;
    size_t need = (512 + 2*(size_t)N + (size_t)NE) * sizeof(float);
    if (ws_size < need) return;

    int nbE = (NE + 255) / 256;
    int nbN = (N + 255) / 256;
    k_mlp<<<nbE + nbN, 256, 0, stream>>>(node_feat, edge_attr,
        node_W1, node_b1, node_W2, node_b2,
        edge_W1, edge_b1, edge_W2, edge_b2,
        inits, update, w, N, NE, nbE);
    k_circ<<<nbN, 256, 0, stream>>>(w,
        upd_W1, upd_b1, upd_W2, upd_b2, ln_g, ln_b,
        sub_nodes, sub_edges, batch,
        head_W1, head_b1, head_W2, head_b2,
        (float*)d_out, N);
}

// Round 12
// 44.248 us; speedup vs baseline: 2.0053x; 1.0036x over previous
//
#include <hip/hip_runtime.h>
#include <math.h>

static constexpr float PI_F = 3.14159265358979323846f;

// dims: N=32768 nodes, NE=3N edges, H=128, PQC=2
// ws layout (floats):
//   [0..96)    seg: 32 x {sum0, sum1, count}
//   [96]       int counter (last-block election)
//   [128..384) phi table: 64 x {|p0|^2, |p1|^2, Re(p0 p1*), Im(p0 p1*)}
//   [384..416) U: 4x4 complex row-major [k][c][re,im]
//   [512..512+2N)      nf  (float2 per node: a,b)
//   [512+2N..512+2N+NE) ef1 (edge a only; edge b provably drops out)

__device__ inline void rot2(float p, float t, float o, float R[2][2][2]) {
    // Rot(p,t,o) = Rz(o) Ry(t) Rz(p)
    float ct = cosf(0.5f*t), st = sinf(0.5f*t);
    float apo = 0.5f*(p+o), amo = 0.5f*(p-o);
    R[0][0][0] =  ct*cosf(apo); R[0][0][1] = -ct*sinf(apo);
    R[0][1][0] = -st*cosf(amo); R[0][1][1] = -st*sinf(amo);
    R[1][0][0] =  st*cosf(amo); R[1][0][1] = -st*sinf(amo);
    R[1][1][0] =  ct*cosf(apo); R[1][1][1] =  ct*sinf(apo);
}

// --- kernel A: setup (block 0) + edge MLP (blocks [0,nbE)) + node MLP (rest) ---
// Weights read from global at wave-uniform indices -> s_load. h-loop ROLLED
// (unroll 4) + streaming accumulator: ~8x smaller code, ~1/3 the VGPRs of the
// t[128] version (I$-resident, 6-8 waves/SIMD). Math order identical.
__global__ __launch_bounds__(256) void k_mlp(
    const float* __restrict__ node_feat, const float* __restrict__ edge_attr,
    const float* __restrict__ nW1, const float* __restrict__ nb1,
    const float* __restrict__ nW2, const float* __restrict__ nb2,
    const float* __restrict__ eW1, const float* __restrict__ eb1,
    const float* __restrict__ eW2, const float* __restrict__ eb2,
    const float* __restrict__ inits, const float* __restrict__ update,
    float* __restrict__ ws, int N, int NE, int nbE)
{
    const int tid = threadIdx.x;
    const int blk = blockIdx.x;

    if (blk == 0) {
        // zero segment accumulators + counter (harness doesn't re-poison between replays)
        if (tid < 96) ws[tid] = 0.f;
        if (tid == 96) ((int*)ws)[96] = 0;
        if (tid < 64) {
            // phi table: wire-7 state for control pattern tid
            // bits 0..2 = wires 0,1,2 (CRY ctrl), bits 3..5 = wires 4,5,6 (CRX/CRZ ctrl)
            float cx = cosf(0.5f*inits[0]), sx = sinf(0.5f*inits[0]);
            float cy = cosf(0.5f*inits[1]), sy = sinf(0.5f*inits[1]);
            float cz = cosf(0.5f*inits[2]), sz = sinf(0.5f*inits[2]);
            float v0r = 1.f, v0i = 0.f, v1r = 0.f, v1i = 0.f;
            #pragma unroll
            for (int i = 0; i < 3; ++i) {
                int xb = (tid >> (3+i)) & 1;
                int yb = (tid >> i) & 1;
                if (xb) { // Rx
                    float n0r = cx*v0r + sx*v1i, n0i = cx*v0i - sx*v1r;
                    float n1r = sx*v0i + cx*v1r, n1i = -sx*v0r + cx*v1i;
                    v0r=n0r; v0i=n0i; v1r=n1r; v1i=n1i;
                }
                if (yb) { // Ry
                    float n0r = cy*v0r - sy*v1r, n0i = cy*v0i - sy*v1i;
                    float n1r = sy*v0r + cy*v1r, n1i = sy*v0i + cy*v1i;
                    v0r=n0r; v0i=n0i; v1r=n1r; v1i=n1i;
                }
                if (xb) { // Rz
                    float n0r = cz*v0r + sz*v0i, n0i = cz*v0i - sz*v0r;
                    float n1r = cz*v1r - sz*v1i, n1i = cz*v1i + sz*v1r;
                    v0r=n0r; v0i=n0i; v1r=n1r; v1i=n1i;
                }
            }
            ws[128 + tid*4 + 0] = v0r*v0r + v0i*v0i;
            ws[128 + tid*4 + 1] = v1r*v1r + v1i*v1i;
            ws[128 + tid*4 + 2] = v0r*v1r + v0i*v1i;   // Re(p0 p1*)
            ws[128 + tid*4 + 3] = v0i*v1r - v0r*v1i;   // Im(p0 p1*)
        } else if (tid == 64) {
            // U = CNOT(7,3) CNOT(3,7) (Ra (x) Rb), basis idx = 2*w3 + w7; row perm {0,2,3,1}
            float Ra[2][2][2], Rb[2][2][2];
            rot2(update[0], update[1], update[2], Ra);
            rot2(update[3], update[4], update[5], Rb);
            const int src[4] = {0, 2, 3, 1};
            #pragma unroll
            for (int k = 0; k < 4; ++k) {
                int r = src[k], r3 = r >> 1, r7 = r & 1;
                #pragma unroll
                for (int c = 0; c < 4; ++c) {
                    int c3 = c >> 1, c7 = c & 1;
                    float ar = Ra[r3][c3][0], ai = Ra[r3][c3][1];
                    float br = Rb[r7][c7][0], bi = Rb[r7][c7][1];
                    ws[384 + (k*4+c)*2 + 0] = ar*br - ai*bi;
                    ws[384 + (k*4+c)*2 + 1] = ar*bi + ai*br;
                }
            }
        }
    }

    if (blk < nbE) {
        // ---- edge MLP: (8->128->1), only output col 0 (edge b drops out of circuit) ----
        int e = blk * 256 + tid;
        if (e >= NE) return;
        const float4* xp = (const float4*)(edge_attr + (size_t)e * 8);
        float4 v0 = xp[0], v1 = xp[1];
        float x[8] = {v0.x,v0.y,v0.z,v0.w, v1.x,v1.y,v1.z,v1.w};
        float acc = 0.f;
        #pragma unroll 4
        for (int h = 0; h < 128; ++h) {
            float tt = eb1[h];
            #pragma unroll
            for (int i = 0; i < 8; ++i) tt = fmaf(x[i], eW1[i*128 + h], tt);
            float lt = tt > 0.f ? tt : 0.01f * tt;
            acc = fmaf(lt, eW2[2*h], acc);
        }
        ws[512 + 2*(size_t)N + e] = tanhf(acc + eb2[0]) * PI_F;
    } else {
        // ---- node MLP: (16->128->2) ----
        int n = (blk - nbE) * 256 + tid;
        if (n >= N) return;
        const float4* xp = (const float4*)(node_feat + (size_t)n * 16);
        float4 v0 = xp[0], v1 = xp[1], v2 = xp[2], v3 = xp[3];
        float x[16] = {v0.x,v0.y,v0.z,v0.w, v1.x,v1.y,v1.z,v1.w,
                       v2.x,v2.y,v2.z,v2.w, v3.x,v3.y,v3.z,v3.w};
        float a0 = 0.f, a1 = 0.f;
        #pragma unroll 4
        for (int h = 0; h < 128; ++h) {
            float tt = nb1[h];
            #pragma unroll
            for (int i = 0; i < 16; ++i) tt = fmaf(x[i], nW1[i*128 + h], tt);
            float lt = tt > 0.f ? tt : 0.01f * tt;
            a0 = fmaf(lt, nW2[2*h],   a0);
            a1 = fmaf(lt, nW2[2*h+1], a1);
        }
        float2 o;
        o.x = tanhf(a0 + nb2[0]) * PI_F;
        o.y = tanhf(a1 + nb2[1]) * PI_F;
        ((float2*)(ws + 512))[n] = o;
    }
}

// --- kernel B: analytic circuit + upd MLP + LN + segment reduce + (last block) head ---
__global__ __launch_bounds__(256) void k_circ(
    float* __restrict__ ws,
    const float* __restrict__ uW1, const float* __restrict__ ub1,
    const float* __restrict__ uW2, const float* __restrict__ ub2,
    const float* __restrict__ lng, const float* __restrict__ lnb,
    const int* __restrict__ sub_nodes, const int* __restrict__ sub_edges,
    const int* __restrict__ batch,
    const float* __restrict__ hW1, const float* __restrict__ hb1,
    const float* __restrict__ hW2, const float* __restrict__ hb2,
    float* __restrict__ out, int N)
{
    const int tid = threadIdx.x;
    const float2* nf  = (const float2*)(ws + 512);
    const float* ef1  = ws + 512 + 2*(size_t)N;
    const float4* phi4 = (const float4*)(ws + 128);
    const float* U    = ws + 384;

    int n0 = blockIdx.x * 256 + tid;
    bool valid = n0 < N;
    int n = valid ? n0 : N - 1;

    const int4 sn = ((const int4*)sub_nodes)[n];
    int se0 = sub_edges[3*(size_t)n+0], se1 = sub_edges[3*(size_t)n+1], se2 = sub_edges[3*(size_t)n+2];

    // control-wire probability weights (only a-angle matters; cos^2(a/2)=(1+cos a)/2)
    float pe[3][2], pn[3][2];
    {
        float c0 = cosf(ef1[se0]), c1 = cosf(ef1[se1]), c2 = cosf(ef1[se2]);
        pe[0][0]=0.5f*(1.f+c0); pe[0][1]=0.5f*(1.f-c0);
        pe[1][0]=0.5f*(1.f+c1); pe[1][1]=0.5f*(1.f-c1);
        pe[2][0]=0.5f*(1.f+c2); pe[2][1]=0.5f*(1.f-c2);
        float d0 = cosf(nf[sn.y].x), d1 = cosf(nf[sn.z].x), d2 = cosf(nf[sn.w].x);
        pn[0][0]=0.5f*(1.f+d0); pn[0][1]=0.5f*(1.f-d0);
        pn[1][0]=0.5f*(1.f+d1); pn[1][1]=0.5f*(1.f-d1);
        pn[2][0]=0.5f*(1.f+d2); pn[2][1]=0.5f*(1.f-d2);
    }
    float E[8], Nw[8];
    #pragma unroll
    for (int m = 0; m < 8; ++m) {
        E[m]  = pe[0][m&1] * pe[1][(m>>1)&1] * pe[2][(m>>2)&1];
        Nw[m] = pn[0][m&1] * pn[1][(m>>1)&1] * pn[2][(m>>2)&1];
    }
    float S0 = 0.f, S1 = 0.f, Sr = 0.f, Si = 0.f;
    #pragma unroll
    for (int m = 0; m < 64; ++m) {
        float W = E[m & 7] * Nw[m >> 3];
        float4 g = phi4[m];
        S0 = fmaf(W, g.x, S0); S1 = fmaf(W, g.y, S1);
        Sr = fmaf(W, g.z, Sr); Si = fmaf(W, g.w, Si);
    }
    // center qubit + T = U (q3 (x) I)
    float2 nfc = nf[sn.x];
    float ca = cosf(0.5f*nfc.x), sa = sinf(0.5f*nfc.x);
    float cb = cosf(0.5f*nfc.y), sb = sinf(0.5f*nfc.y);
    float q0r = ca*cb, q0i = -ca*sb, q1r = sa*cb, q1i = sa*sb;
    float P[4];
    #pragma unroll
    for (int k = 0; k < 4; ++k) {
        float T0r, T0i, T1r, T1i;
        {
            float u0r = U[(k*4+0)*2], u0i = U[(k*4+0)*2+1];
            float u1r = U[(k*4+2)*2], u1i = U[(k*4+2)*2+1];
            T0r = u0r*q0r - u0i*q0i + u1r*q1r - u1i*q1i;
            T0i = u0r*q0i + u0i*q0r + u1r*q1i + u1i*q1r;
        }
        {
            float u0r = U[(k*4+1)*2], u0i = U[(k*4+1)*2+1];
            float u1r = U[(k*4+3)*2], u1i = U[(k*4+3)*2+1];
            T1r = u0r*q0r - u0i*q0i + u1r*q1r - u1i*q1i;
            T1i = u0r*q0i + u0i*q0r + u1r*q1i + u1i*q1r;
        }
        float Ar = T0r*T1r + T0i*T1i, Ai = T0i*T1r - T0r*T1i;
        P[k] = (T0r*T0r + T0i*T0i)*S0 + (T1r*T1r + T1i*T1i)*S1 + 2.f*(Ar*Sr - Ai*Si);
    }
    // upd MLP (6->128->2), rolled h-loop, streaming accumulator
    float in6[6] = {nfc.x, nfc.y, P[0], P[1], P[2], P[3]};
    float u0 = 0.f, u1 = 0.f;
    #pragma unroll 4
    for (int h = 0; h < 128; ++h) {
        float tt = ub1[h];
        #pragma unroll
        for (int i = 0; i < 6; ++i) tt = fmaf(in6[i], uW1[i*128 + h], tt);
        float lt = tt > 0.f ? tt : 0.01f * tt;
        u0 = fmaf(lt, uW2[2*h],   u0);
        u1 = fmaf(lt, uW2[2*h+1], u1);
    }
    // x = 1.5*nf + 0.5*upd (centers == arange(N)); LayerNorm over 2 features
    float x0 = 1.5f*nfc.x + 0.5f*(tanhf(u0 + ub2[0]) * PI_F);
    float x1 = 1.5f*nfc.y + 0.5f*(tanhf(u1 + ub2[1]) * PI_F);
    float mu = 0.5f*(x0 + x1);
    float d  = x0 - mu;
    float inv = 1.0f / sqrtf(d*d + 1e-5f);
    float wv  = valid ? 1.f : 0.f;
    float xn0 = ( d*inv*lng[0] + lnb[0]) * wv;
    float xn1 = (-d*inv*lng[1] + lnb[1]) * wv;
    int bs = batch[n];

    // segment accumulate: wave-uniform fast path (batch is sorted), per-lane fallback
    bool uni = __all(bs == __shfl(bs, 0));
    if (uni) {
        float r0 = xn0, r1 = xn1, rc = wv;
        #pragma unroll
        for (int off = 32; off >= 1; off >>= 1) {
            r0 += __shfl_xor(r0, off); r1 += __shfl_xor(r1, off); rc += __shfl_xor(rc, off);
        }
        if ((tid & 63) == 0) {
            atomicAdd(&ws[bs*3+0], r0);
            atomicAdd(&ws[bs*3+1], r1);
            atomicAdd(&ws[bs*3+2], rc);
        }
    } else if (valid) {
        atomicAdd(&ws[bs*3+0], xn0);
        atomicAdd(&ws[bs*3+1], xn1);
        atomicAdd(&ws[bs*3+2], 1.f);
    }

    // last-block election -> head MLP (2->2 leaky 2->2) on segment means
    __shared__ int sLast;
    __threadfence();
    __syncthreads();
    if (tid == 0) {
        int old = atomicAdd((int*)ws + 96, 1);
        sLast = (old == (int)gridDim.x - 1) ? 1 : 0;
    }
    __syncthreads();
    if (sLast && tid < 32) {
        // device-scope atomic reads for cross-XCD coherence
        float cnt = atomicAdd(&ws[tid*3+2], 0.f);
        float iv  = cnt > 0.f ? 1.f/cnt : 0.f;
        float g0  = atomicAdd(&ws[tid*3+0], 0.f) * iv;
        float g1  = atomicAdd(&ws[tid*3+1], 0.f) * iv;
        float h0, h1;
        {
            float a = hb1[0] + g0*hW1[0] + g1*hW1[2];
            float b = hb1[1] + g0*hW1[1] + g1*hW1[3];
            h0 = a > 0.f ? a : 0.01f*a;
            h1 = b > 0.f ? b : 0.01f*b;
        }
        out[tid*2+0] = hb2[0] + h0*hW2[0] + h1*hW2[2];
        out[tid*2+1] = hb2[1] + h0*hW2[1] + h1*hW2[3];
    }
}

extern "C" void kernel_launch(void* const* d_in, const int* in_sizes, int n_in,
                              void* d_out, int out_size, void* d_ws, size_t ws_size,
                              hipStream_t stream)
{
    const float* node_feat = (const float*)d_in[0];
    const float* edge_attr = (const float*)d_in[1];
    const float* node_W1 = (const float*)d_in[2];
    const float* node_b1 = (const float*)d_in[3];
    const float* node_W2 = (const float*)d_in[4];
    const float* node_b2 = (const float*)d_in[5];
    const float* edge_W1 = (const float*)d_in[6];
    const float* edge_b1 = (const float*)d_in[7];
    const float* edge_W2 = (const float*)d_in[8];
    const float* edge_b2 = (const float*)d_in[9];
    const float* inits   = (const float*)d_in[10];
    const float* update  = (const float*)d_in[11];
    const float* upd_W1  = (const float*)d_in[12];
    const float* upd_b1  = (const float*)d_in[13];
    const float* upd_W2  = (const float*)d_in[14];
    const float* upd_b2  = (const float*)d_in[15];
    const float* ln_g    = (const float*)d_in[16];
    const float* ln_b    = (const float*)d_in[17];
    const float* head_W1 = (const float*)d_in[18];
    const float* head_b1 = (const float*)d_in[19];
    const float* head_W2 = (const float*)d_in[20];
    const float* head_b2 = (const float*)d_in[21];
    const int* sub_nodes = (const int*)d_in[22];
    const int* sub_edges = (const int*)d_in[23];
    const int* batch     = (const int*)d_in[24];

    int N  = in_sizes[24];      // 32768
    int NE = in_sizes[1] / 8;   // 98304

    float* w = (float*)d_ws;
    size_t need = (512 + 2*(size_t)N + (size_t)NE) * sizeof(float);
    if (ws_size < need) return;

    int nbE = (NE + 255) / 256;
    int nbN = (N + 255) / 256;
    k_mlp<<<nbE + nbN, 256, 0, stream>>>(node_feat, edge_attr,
        node_W1, node_b1, node_W2, node_b2,
        edge_W1, edge_b1, edge_W2, edge_b2,
        inits, update, w, N, NE, nbE);
    k_circ<<<nbN, 256, 0, stream>>>(w,
        upd_W1, upd_b1, upd_W2, upd_b2, ln_g, ln_b,
        sub_nodes, sub_edges, batch,
        head_W1, head_b1, head_W2, head_b2,
        (float*)d_out, N);
}